// Round 1
// baseline (2978.491 us; speedup 1.0000x reference)
//
#include <hip/hip_runtime.h>

#define DIM 128

// ---------------- K1: h = x @ W_lin^T + b_lin ----------------
// 64 rows x 128 cols per block, 256 threads, each thread 4x8 outputs.
__global__ __launch_bounds__(256) void k_gemm_h(
    const float* __restrict__ x, const float* __restrict__ W,
    const float* __restrict__ b, float* __restrict__ h, int n)
{
    __shared__ float wT[128][132];   // wT[k][j] = W[j][k], padded for alignment
    __shared__ float xT[128][68];    // xT[k][r] = x[row0+r][k]
    const int tid  = threadIdx.x;
    const int row0 = blockIdx.x * 64;

    for (int i = 0; i < 64; ++i) {
        int g = tid + i * 256;                 // 16384 = 128*128
        wT[g & 127][g >> 7] = W[g];
    }
    for (int i = 0; i < 32; ++i) {
        int g = tid + i * 256;                 // 8192 = 64*128
        int r = g >> 7, k = g & 127;
        int row = row0 + r;
        xT[k][r] = (row < n) ? x[(size_t)row * DIM + k] : 0.0f;
    }
    __syncthreads();

    const int c = (tid & 15) * 8;              // col base
    const int r = (tid >> 4) * 4;              // row base

    float acc[4][8];
#pragma unroll
    for (int i = 0; i < 4; ++i)
#pragma unroll
        for (int j = 0; j < 8; ++j) acc[i][j] = 0.0f;

#pragma unroll 4
    for (int k = 0; k < 128; ++k) {
        const float4 xv = *(const float4*)&xT[k][r];
        const float4 wa = *(const float4*)&wT[k][c];
        const float4 wb = *(const float4*)&wT[k][c + 4];
        const float xr[4] = {xv.x, xv.y, xv.z, xv.w};
        const float wc[8] = {wa.x, wa.y, wa.z, wa.w, wb.x, wb.y, wb.z, wb.w};
#pragma unroll
        for (int i = 0; i < 4; ++i)
#pragma unroll
            for (int j = 0; j < 8; ++j)
                acc[i][j] = fmaf(xr[i], wc[j], acc[i][j]);
    }

    const float4 b0 = *(const float4*)&b[c];
    const float4 b1 = *(const float4*)&b[c + 4];
#pragma unroll
    for (int i = 0; i < 4; ++i) {
        int row = row0 + r + i;
        if (row < n) {
            float4 o0 = {acc[i][0] + b0.x, acc[i][1] + b0.y,
                         acc[i][2] + b0.z, acc[i][3] + b0.w};
            float4 o1 = {acc[i][4] + b1.x, acc[i][5] + b1.y,
                         acc[i][6] + b1.z, acc[i][7] + b1.w};
            *(float4*)&h[(size_t)row * DIM + c]     = o0;
            *(float4*)&h[(size_t)row * DIM + c + 4] = o1;
        }
    }
}

// ---------------- K2: per-node al, ar, beta ----------------
// one wave (64 lanes) per node row
__global__ __launch_bounds__(256) void k_node_vec(
    const float* __restrict__ x, const float* __restrict__ h,
    const float* __restrict__ Wc, const float* __restrict__ bc,   // (3,128),(3,)
    const float* __restrict__ alw, const float* __restrict__ alb, // (2,128),(2,)
    const float* __restrict__ arw, const float* __restrict__ arb,
    float* __restrict__ albuf, float* __restrict__ arbuf,
    float* __restrict__ betab, int n)
{
    int wid  = blockIdx.x * 4 + (threadIdx.x >> 6);
    int lane = threadIdx.x & 63;
    if (wid >= n) return;

    const float2 x2 = *(const float2*)(x + (size_t)wid * DIM + lane * 2);
    const float2 h2 = *(const float2*)(h + (size_t)wid * DIM + lane * 2);

    float p[7];
    {
        float2 w;
        w = *(const float2*)(alw + 0 * DIM + lane * 2); p[0] = h2.x * w.x + h2.y * w.y;
        w = *(const float2*)(alw + 1 * DIM + lane * 2); p[1] = h2.x * w.x + h2.y * w.y;
        w = *(const float2*)(arw + 0 * DIM + lane * 2); p[2] = h2.x * w.x + h2.y * w.y;
        w = *(const float2*)(arw + 1 * DIM + lane * 2); p[3] = h2.x * w.x + h2.y * w.y;
        w = *(const float2*)(Wc  + 0 * DIM + lane * 2); p[4] = x2.x * w.x + x2.y * w.y;
        w = *(const float2*)(Wc  + 1 * DIM + lane * 2); p[5] = x2.x * w.x + x2.y * w.y;
        w = *(const float2*)(Wc  + 2 * DIM + lane * 2); p[6] = x2.x * w.x + x2.y * w.y;
    }
#pragma unroll
    for (int i = 0; i < 7; ++i) {
        float v = p[i];
#pragma unroll
        for (int o = 32; o > 0; o >>= 1) v += __shfl_xor(v, o);
        p[i] = v;
    }
    if (lane == 0) {
        albuf[wid * 2 + 0] = p[0] + alb[0];
        albuf[wid * 2 + 1] = p[1] + alb[1];
        arbuf[wid * 2 + 0] = p[2] + arb[0];
        arbuf[wid * 2 + 1] = p[3] + arb[1];
        float c0 = p[4] + bc[0], c1 = p[5] + bc[1], c2 = p[6] + bc[2];
        float mx = fmaxf(c0, fmaxf(c1, c2));
        float e0 = __expf(c0 - mx), e1 = __expf(c1 - mx), e2 = __expf(c2 - mx);
        float s = e0 + e1 + e2;
        betab[wid * 3 + 0] = e0 / s;
        betab[wid * 3 + 1] = e1 / s;
        betab[wid * 3 + 2] = e2 / s;
    }
}

// ---------------- K3: per-edge exp(logit) + segment denom ----------------
__global__ __launch_bounds__(256) void k_edge_logit(
    const int* __restrict__ ei, const float* __restrict__ albuf,
    const float* __restrict__ arbuf, const float* __restrict__ alpha,
    float* __restrict__ exbuf, float* __restrict__ denom, int m, int e)
{
    int t = blockIdx.x * 256 + threadIdx.x;
    if (t >= e) return;
    int dst = ei[t];
    int src = ei[e + t];
    float l  = alpha[m] * (albuf[src * 2 + m] + arbuf[dst * 2 + m]);
    float ex = __expf(l);
    exbuf[t] = ex;
    unsafeAtomicAdd(&denom[dst], ex);
}

// ---------------- K4: weighted scatter out[dst] += w * h[src] ----------------
// one wave per edge; beta[dst][m] folded into the edge weight
__global__ __launch_bounds__(256) void k_edge_scatter(
    const int* __restrict__ ei, const float* __restrict__ h,
    const float* __restrict__ exbuf, const float* __restrict__ denom,
    const float* __restrict__ betab, float* __restrict__ out, int m, int e)
{
    int ew = blockIdx.x * 4 + (threadIdx.x >> 6);
    if (ew >= e) return;
    int lane = threadIdx.x & 63;
    int dst = ei[ew];
    int src = ei[e + ew];
    float w = betab[dst * 3 + m] * exbuf[ew] / (denom[dst] + 1e-16f);
    const float2 hv = *(const float2*)(h + (size_t)src * DIM + lane * 2);
    unsafeAtomicAdd(&out[(size_t)dst * DIM + lane * 2 + 0], w * hv.x);
    unsafeAtomicAdd(&out[(size_t)dst * DIM + lane * 2 + 1], w * hv.y);
}

// ---------------- K5: out = relu(out + beta[:,2] * h) ----------------
__global__ __launch_bounds__(256) void k_final(
    const float* __restrict__ h, const float* __restrict__ betab,
    float* __restrict__ out, int total4)
{
    int t = blockIdx.x * 256 + threadIdx.x;
    if (t >= total4) return;
    size_t idx = (size_t)t * 4;
    int row = (int)(idx >> 7);
    float4 hv = *(const float4*)(h + idx);
    float4 o  = *(const float4*)(out + idx);
    float b2  = betab[row * 3 + 2];
    o.x = fmaxf(fmaf(b2, hv.x, o.x), 0.0f);
    o.y = fmaxf(fmaf(b2, hv.y, o.y), 0.0f);
    o.z = fmaxf(fmaf(b2, hv.z, o.z), 0.0f);
    o.w = fmaxf(fmaf(b2, hv.w, o.w), 0.0f);
    *(float4*)(out + idx) = o;
}

extern "C" void kernel_launch(void* const* d_in, const int* in_sizes, int n_in,
                              void* d_out, int out_size, void* d_ws, size_t ws_size,
                              hipStream_t stream)
{
    const float* x     = (const float*)d_in[0];
    const int*   ei1   = (const int*)d_in[1];
    const int*   ei2   = (const int*)d_in[2];
    const float* W_lin = (const float*)d_in[3];
    const float* b_lin = (const float*)d_in[4];
    const float* W_cv  = (const float*)d_in[5];
    const float* b_cv  = (const float*)d_in[6];
    const float* alw   = (const float*)d_in[7];
    const float* alb   = (const float*)d_in[8];
    const float* arw   = (const float*)d_in[9];
    const float* arb   = (const float*)d_in[10];
    const float* alpha = (const float*)d_in[11];

    const int N = in_sizes[0] / DIM;
    const int E = in_sizes[1] / 2;

    float* out = (float*)d_out;

    // workspace layout (floats)
    float* h     = (float*)d_ws;                  // N*128
    float* albuf = h     + (size_t)N * DIM;       // 2N
    float* arbuf = albuf + (size_t)2 * N;         // 2N
    float* betab = arbuf + (size_t)2 * N;         // 3N
    float* denom = betab + (size_t)3 * N;         // 2N
    float* exbuf = denom + (size_t)2 * N;         // 2E

    hipMemsetAsync(out,   0, (size_t)N * DIM * sizeof(float), stream);
    hipMemsetAsync(denom, 0, (size_t)2 * N * sizeof(float),  stream);

    // K1: h
    k_gemm_h<<<(N + 63) / 64, 256, 0, stream>>>(x, W_lin, b_lin, h, N);

    // K2: al/ar/beta
    k_node_vec<<<(N + 3) / 4, 256, 0, stream>>>(x, h, W_cv, b_cv, alw, alb,
                                                arw, arb, albuf, arbuf, betab, N);

    // K3: edge logits + denominators
    k_edge_logit<<<(E + 255) / 256, 256, 0, stream>>>(ei1, albuf, arbuf, alpha,
                                                      exbuf,     denom,     0, E);
    k_edge_logit<<<(E + 255) / 256, 256, 0, stream>>>(ei2, albuf, arbuf, alpha,
                                                      exbuf + E, denom + N, 1, E);

    // K4: weighted scatter (beta folded in)
    k_edge_scatter<<<(E + 3) / 4, 256, 0, stream>>>(ei1, h, exbuf,     denom,
                                                    betab, out, 0, E);
    k_edge_scatter<<<(E + 3) / 4, 256, 0, stream>>>(ei2, h, exbuf + E, denom + N,
                                                    betab, out, 1, E);

    // K5: add self channel + relu
    k_final<<<((N * DIM / 4) + 255) / 256, 256, 0, stream>>>(h, betab, out,
                                                             N * DIM / 4);
}

// Round 2
// 822.271 us; speedup vs baseline: 3.6223x; 3.6223x over previous
//
#include <hip/hip_runtime.h>

#define DIM 128

// ---------------- K1: h = x @ W_lin^T + b_lin ----------------
__global__ __launch_bounds__(256) void k_gemm_h(
    const float* __restrict__ x, const float* __restrict__ W,
    const float* __restrict__ b, float* __restrict__ h, int n)
{
    __shared__ float wT[128][132];
    __shared__ float xT[128][68];
    const int tid  = threadIdx.x;
    const int row0 = blockIdx.x * 64;

    for (int i = 0; i < 64; ++i) {
        int g = tid + i * 256;
        wT[g & 127][g >> 7] = W[g];
    }
    for (int i = 0; i < 32; ++i) {
        int g = tid + i * 256;
        int r = g >> 7, k = g & 127;
        int row = row0 + r;
        xT[k][r] = (row < n) ? x[(size_t)row * DIM + k] : 0.0f;
    }
    __syncthreads();

    const int c = (tid & 15) * 8;
    const int r = (tid >> 4) * 4;

    float acc[4][8];
#pragma unroll
    for (int i = 0; i < 4; ++i)
#pragma unroll
        for (int j = 0; j < 8; ++j) acc[i][j] = 0.0f;

#pragma unroll 4
    for (int k = 0; k < 128; ++k) {
        const float4 xv = *(const float4*)&xT[k][r];
        const float4 wa = *(const float4*)&wT[k][c];
        const float4 wb = *(const float4*)&wT[k][c + 4];
        const float xr[4] = {xv.x, xv.y, xv.z, xv.w};
        const float wc[8] = {wa.x, wa.y, wa.z, wa.w, wb.x, wb.y, wb.z, wb.w};
#pragma unroll
        for (int i = 0; i < 4; ++i)
#pragma unroll
            for (int j = 0; j < 8; ++j)
                acc[i][j] = fmaf(xr[i], wc[j], acc[i][j]);
    }

    const float4 b0 = *(const float4*)&b[c];
    const float4 b1 = *(const float4*)&b[c + 4];
#pragma unroll
    for (int i = 0; i < 4; ++i) {
        int row = row0 + r + i;
        if (row < n) {
            float4 o0 = {acc[i][0] + b0.x, acc[i][1] + b0.y,
                         acc[i][2] + b0.z, acc[i][3] + b0.w};
            float4 o1 = {acc[i][4] + b1.x, acc[i][5] + b1.y,
                         acc[i][6] + b1.z, acc[i][7] + b1.w};
            *(float4*)&h[(size_t)row * DIM + c]     = o0;
            *(float4*)&h[(size_t)row * DIM + c + 4] = o1;
        }
    }
}

// ---------------- K2: per-node al, ar, beta ----------------
__global__ __launch_bounds__(256) void k_node_vec(
    const float* __restrict__ x, const float* __restrict__ h,
    const float* __restrict__ Wc, const float* __restrict__ bc,
    const float* __restrict__ alw, const float* __restrict__ alb,
    const float* __restrict__ arw, const float* __restrict__ arb,
    float* __restrict__ albuf, float* __restrict__ arbuf,
    float* __restrict__ betab, int n)
{
    int wid  = blockIdx.x * 4 + (threadIdx.x >> 6);
    int lane = threadIdx.x & 63;
    if (wid >= n) return;

    const float2 x2 = *(const float2*)(x + (size_t)wid * DIM + lane * 2);
    const float2 h2 = *(const float2*)(h + (size_t)wid * DIM + lane * 2);

    float p[7];
    {
        float2 w;
        w = *(const float2*)(alw + 0 * DIM + lane * 2); p[0] = h2.x * w.x + h2.y * w.y;
        w = *(const float2*)(alw + 1 * DIM + lane * 2); p[1] = h2.x * w.x + h2.y * w.y;
        w = *(const float2*)(arw + 0 * DIM + lane * 2); p[2] = h2.x * w.x + h2.y * w.y;
        w = *(const float2*)(arw + 1 * DIM + lane * 2); p[3] = h2.x * w.x + h2.y * w.y;
        w = *(const float2*)(Wc  + 0 * DIM + lane * 2); p[4] = x2.x * w.x + x2.y * w.y;
        w = *(const float2*)(Wc  + 1 * DIM + lane * 2); p[5] = x2.x * w.x + x2.y * w.y;
        w = *(const float2*)(Wc  + 2 * DIM + lane * 2); p[6] = x2.x * w.x + x2.y * w.y;
    }
#pragma unroll
    for (int i = 0; i < 7; ++i) {
        float v = p[i];
#pragma unroll
        for (int o = 32; o > 0; o >>= 1) v += __shfl_xor(v, o);
        p[i] = v;
    }
    if (lane == 0) {
        albuf[wid * 2 + 0] = p[0] + alb[0];
        albuf[wid * 2 + 1] = p[1] + alb[1];
        arbuf[wid * 2 + 0] = p[2] + arb[0];
        arbuf[wid * 2 + 1] = p[3] + arb[1];
        float c0 = p[4] + bc[0], c1 = p[5] + bc[1], c2 = p[6] + bc[2];
        float mx = fmaxf(c0, fmaxf(c1, c2));
        float e0 = __expf(c0 - mx), e1 = __expf(c1 - mx), e2 = __expf(c2 - mx);
        float s = e0 + e1 + e2;
        betab[wid * 3 + 0] = e0 / s;
        betab[wid * 3 + 1] = e1 / s;
        betab[wid * 3 + 2] = e2 / s;
    }
}

// ---------------- K3: degree count ----------------
__global__ __launch_bounds__(256) void k_count(
    const int* __restrict__ ei, int* __restrict__ cnt, int e)
{
    int t = blockIdx.x * 256 + threadIdx.x;
    if (t >= e) return;
    atomicAdd(&cnt[ei[t]], 1);
}

// ---------------- K4a/b/c: exclusive scan (2-level) ----------------
__global__ __launch_bounds__(256) void k_scan1(
    const int* __restrict__ cnt, int* __restrict__ excl,
    int* __restrict__ bsum, int n)
{
    __shared__ int sh[256];
    int t = threadIdx.x;
    int base = blockIdx.x * 1024 + t * 4;
    int v0 = (base + 0 < n) ? cnt[base + 0] : 0;
    int v1 = (base + 1 < n) ? cnt[base + 1] : 0;
    int v2 = (base + 2 < n) ? cnt[base + 2] : 0;
    int v3 = (base + 3 < n) ? cnt[base + 3] : 0;
    int s1 = v0 + v1, s2 = s1 + v2, s3 = s2 + v3;
    sh[t] = s3;
    __syncthreads();
    for (int off = 1; off < 256; off <<= 1) {
        int a = (t >= off) ? sh[t - off] : 0;
        __syncthreads();
        sh[t] += a;
        __syncthreads();
    }
    int eb = sh[t] - s3;
    if (t == 255) bsum[blockIdx.x] = sh[255];
    if (base + 0 < n) excl[base + 0] = eb;
    if (base + 1 < n) excl[base + 1] = eb + v0;
    if (base + 2 < n) excl[base + 2] = eb + s1;
    if (base + 3 < n) excl[base + 3] = eb + s2;
}

__global__ __launch_bounds__(256) void k_scan2(int* __restrict__ bsum, int nb)
{
    __shared__ int sh[256];
    int t = threadIdx.x;
    int v = (t < nb) ? bsum[t] : 0;
    sh[t] = v;
    __syncthreads();
    for (int off = 1; off < 256; off <<= 1) {
        int a = (t >= off) ? sh[t - off] : 0;
        __syncthreads();
        sh[t] += a;
        __syncthreads();
    }
    if (t < nb) bsum[t] = sh[t] - v;
}

__global__ __launch_bounds__(256) void k_scan3(
    int* __restrict__ rowptr, const int* __restrict__ bsum,
    int* __restrict__ woff, int n, int e)
{
    int i = blockIdx.x * 256 + threadIdx.x;
    if (i < n) {
        int r = rowptr[i] + bsum[i >> 10];
        rowptr[i] = r;
        woff[i] = r;
    }
    if (i == 0) rowptr[n] = e;
}

// ---------------- K5: CSR fill (src id + exp(logit)) ----------------
__global__ __launch_bounds__(256) void k_fill(
    const int* __restrict__ ei, const float* __restrict__ al,
    const float* __restrict__ ar, const float* __restrict__ alpha,
    int* __restrict__ woff, int* __restrict__ srcs,
    float* __restrict__ exs, int m, int e)
{
    int t = blockIdx.x * 256 + threadIdx.x;
    if (t >= e) return;
    int d = ei[t];
    int s = ei[e + t];
    int pos = atomicAdd(&woff[d], 1);
    srcs[pos] = s;
    exs[pos] = __expf(alpha[m] * (al[s * 2 + m] + ar[d * 2 + m]));
}

// ---------------- K6: fused gather + self + relu ----------------
// one wave per dst node
__global__ __launch_bounds__(256) void k_gather(
    const float* __restrict__ h, const float* __restrict__ betab,
    const int* __restrict__ rp1, const int* __restrict__ src1,
    const float* __restrict__ ex1,
    const int* __restrict__ rp2, const int* __restrict__ src2,
    const float* __restrict__ ex2,
    float* __restrict__ out, int n)
{
    int wid  = blockIdx.x * 4 + (threadIdx.x >> 6);
    if (wid >= n) return;
    int lane = threadIdx.x & 63;

    float b0 = betab[wid * 3 + 0];
    float b1 = betab[wid * 3 + 1];
    float b2 = betab[wid * 3 + 2];

    float2 acc;
    {
        const float2 hv = *(const float2*)(h + (size_t)wid * DIM + lane * 2);
        acc.x = b2 * hv.x;
        acc.y = b2 * hv.y;
    }

#pragma unroll
    for (int m = 0; m < 2; ++m) {
        const int*   rp = m ? rp2 : rp1;
        const int*   sc = m ? src2 : src1;
        const float* ex = m ? ex2 : ex1;
        const float  bm = m ? b1 : b0;

        int s0 = rp[wid], s1 = rp[wid + 1];

        float sum = 0.0f;
        for (int j = s0 + lane; j < s1; j += 64) sum += ex[j];
#pragma unroll
        for (int o = 32; o > 0; o >>= 1) sum += __shfl_xor(sum, o);

        float scale = bm / (sum + 1e-16f);
        for (int j = s0; j < s1; ++j) {
            int s   = sc[j];
            float w = ex[j] * scale;
            const float2 hs = *(const float2*)(h + (size_t)s * DIM + lane * 2);
            acc.x = fmaf(w, hs.x, acc.x);
            acc.y = fmaf(w, hs.y, acc.y);
        }
    }

    float2 o;
    o.x = fmaxf(acc.x, 0.0f);
    o.y = fmaxf(acc.y, 0.0f);
    *(float2*)(out + (size_t)wid * DIM + lane * 2) = o;
}

extern "C" void kernel_launch(void* const* d_in, const int* in_sizes, int n_in,
                              void* d_out, int out_size, void* d_ws, size_t ws_size,
                              hipStream_t stream)
{
    const float* x     = (const float*)d_in[0];
    const int*   ei1   = (const int*)d_in[1];
    const int*   ei2   = (const int*)d_in[2];
    const float* W_lin = (const float*)d_in[3];
    const float* b_lin = (const float*)d_in[4];
    const float* W_cv  = (const float*)d_in[5];
    const float* b_cv  = (const float*)d_in[6];
    const float* alw   = (const float*)d_in[7];
    const float* alb   = (const float*)d_in[8];
    const float* arw   = (const float*)d_in[9];
    const float* arb   = (const float*)d_in[10];
    const float* alpha = (const float*)d_in[11];

    const int N = in_sizes[0] / DIM;
    const int E = in_sizes[1] / 2;

    float* out = (float*)d_out;

    // workspace layout (4-byte elements)
    float* h     = (float*)d_ws;                    // N*128
    float* albuf = h     + (size_t)N * DIM;         // 2N
    float* arbuf = albuf + (size_t)2 * N;           // 2N
    float* betab = arbuf + (size_t)2 * N;           // 3N
    int*   rp1   = (int*)(betab + (size_t)3 * N);   // N+1
    int*   rp2   = rp1 + (N + 1);                   // N+1
    int*   woff  = rp2 + (N + 1);                   // 2N (woff1, woff2)
    int*   bsum  = woff + (size_t)2 * N;            // 512 (256 per metapath)
    int*   srcs1 = bsum + 512;                      // E
    int*   srcs2 = srcs1 + E;                       // E
    float* exs1  = (float*)(srcs2 + E);             // E
    float* exs2  = exs1 + E;                        // E

    int* woff1 = woff;
    int* woff2 = woff + N;
    int* bsum1 = bsum;
    int* bsum2 = bsum + 256;

    const int nb = (N + 1023) / 1024;   // scan blocks (98 for N=100000)

    hipMemsetAsync(woff, 0, (size_t)2 * N * sizeof(int), stream);

    // h = x @ W^T + b
    k_gemm_h<<<(N + 63) / 64, 256, 0, stream>>>(x, W_lin, b_lin, h, N);

    // al / ar / beta
    k_node_vec<<<(N + 3) / 4, 256, 0, stream>>>(x, h, W_cv, b_cv, alw, alb,
                                                arw, arb, albuf, arbuf, betab, N);

    // degree counts
    k_count<<<(E + 255) / 256, 256, 0, stream>>>(ei1, woff1, E);
    k_count<<<(E + 255) / 256, 256, 0, stream>>>(ei2, woff2, E);

    // exclusive scan -> rowptr; copy to woff
    k_scan1<<<nb, 256, 0, stream>>>(woff1, rp1, bsum1, N);
    k_scan1<<<nb, 256, 0, stream>>>(woff2, rp2, bsum2, N);
    k_scan2<<<1, 256, 0, stream>>>(bsum1, nb);
    k_scan2<<<1, 256, 0, stream>>>(bsum2, nb);
    k_scan3<<<(N + 255) / 256, 256, 0, stream>>>(rp1, bsum1, woff1, N, E);
    k_scan3<<<(N + 255) / 256, 256, 0, stream>>>(rp2, bsum2, woff2, N, E);

    // CSR fill with src + exp(logit)
    k_fill<<<(E + 255) / 256, 256, 0, stream>>>(ei1, albuf, arbuf, alpha,
                                                woff1, srcs1, exs1, 0, E);
    k_fill<<<(E + 255) / 256, 256, 0, stream>>>(ei2, albuf, arbuf, alpha,
                                                woff2, srcs2, exs2, 1, E);

    // fused gather + self channel + relu
    k_gather<<<(N + 3) / 4, 256, 0, stream>>>(h, betab,
                                              rp1, srcs1, exs1,
                                              rp2, srcs2, exs2,
                                              out, N);
}

// Round 3
// 753.007 us; speedup vs baseline: 3.9555x; 1.0920x over previous
//
#include <hip/hip_runtime.h>

#define DIM 128

__device__ __forceinline__ unsigned bfbits(float f) {
    unsigned u = __float_as_uint(f);
    return (u + 0x7FFFu + ((u >> 16) & 1u)) >> 16;   // RNE bf16
}

// ---------------- K1: h = x @ W_lin^T + b_lin (+ bf16 copy h2) ----------------
__global__ __launch_bounds__(256) void k_gemm_h(
    const float* __restrict__ x, const float* __restrict__ W,
    const float* __restrict__ b, float* __restrict__ h,
    unsigned* __restrict__ h2, int n)
{
    __shared__ float wT[128][132];
    __shared__ float xT[128][68];
    const int tid  = threadIdx.x;
    const int row0 = blockIdx.x * 64;

    for (int i = 0; i < 64; ++i) {
        int g = tid + i * 256;
        wT[g & 127][g >> 7] = W[g];
    }
    for (int i = 0; i < 32; ++i) {
        int g = tid + i * 256;
        int r = g >> 7, k = g & 127;
        int row = row0 + r;
        xT[k][r] = (row < n) ? x[(size_t)row * DIM + k] : 0.0f;
    }
    __syncthreads();

    const int c = (tid & 15) * 8;
    const int r = (tid >> 4) * 4;

    float acc[4][8];
#pragma unroll
    for (int i = 0; i < 4; ++i)
#pragma unroll
        for (int j = 0; j < 8; ++j) acc[i][j] = 0.0f;

#pragma unroll 4
    for (int k = 0; k < 128; ++k) {
        const float4 xv = *(const float4*)&xT[k][r];
        const float4 wa = *(const float4*)&wT[k][c];
        const float4 wb = *(const float4*)&wT[k][c + 4];
        const float xr[4] = {xv.x, xv.y, xv.z, xv.w};
        const float wc[8] = {wa.x, wa.y, wa.z, wa.w, wb.x, wb.y, wb.z, wb.w};
#pragma unroll
        for (int i = 0; i < 4; ++i)
#pragma unroll
            for (int j = 0; j < 8; ++j)
                acc[i][j] = fmaf(xr[i], wc[j], acc[i][j]);
    }

    const float4 b0 = *(const float4*)&b[c];
    const float4 b1 = *(const float4*)&b[c + 4];
#pragma unroll
    for (int i = 0; i < 4; ++i) {
        int row = row0 + r + i;
        if (row < n) {
            float4 o0 = {acc[i][0] + b0.x, acc[i][1] + b0.y,
                         acc[i][2] + b0.z, acc[i][3] + b0.w};
            float4 o1 = {acc[i][4] + b1.x, acc[i][5] + b1.y,
                         acc[i][6] + b1.z, acc[i][7] + b1.w};
            *(float4*)&h[(size_t)row * DIM + c]     = o0;
            *(float4*)&h[(size_t)row * DIM + c + 4] = o1;
            uint4 p;
            p.x = bfbits(o0.x) | (bfbits(o0.y) << 16);
            p.y = bfbits(o0.z) | (bfbits(o0.w) << 16);
            p.z = bfbits(o1.x) | (bfbits(o1.y) << 16);
            p.w = bfbits(o1.z) | (bfbits(o1.w) << 16);
            *(uint4*)&h2[(size_t)row * 64 + (c >> 1)] = p;
        }
    }
}

// ---------------- K2: per-node al, ar, beta ----------------
__global__ __launch_bounds__(256) void k_node_vec(
    const float* __restrict__ x, const float* __restrict__ h,
    const float* __restrict__ Wc, const float* __restrict__ bc,
    const float* __restrict__ alw, const float* __restrict__ alb,
    const float* __restrict__ arw, const float* __restrict__ arb,
    float* __restrict__ albuf, float* __restrict__ arbuf,
    float* __restrict__ betab, int n)
{
    int wid  = blockIdx.x * 4 + (threadIdx.x >> 6);
    int lane = threadIdx.x & 63;
    if (wid >= n) return;

    const float2 x2 = *(const float2*)(x + (size_t)wid * DIM + lane * 2);
    const float2 h2 = *(const float2*)(h + (size_t)wid * DIM + lane * 2);

    float p[7];
    {
        float2 w;
        w = *(const float2*)(alw + 0 * DIM + lane * 2); p[0] = h2.x * w.x + h2.y * w.y;
        w = *(const float2*)(alw + 1 * DIM + lane * 2); p[1] = h2.x * w.x + h2.y * w.y;
        w = *(const float2*)(arw + 0 * DIM + lane * 2); p[2] = h2.x * w.x + h2.y * w.y;
        w = *(const float2*)(arw + 1 * DIM + lane * 2); p[3] = h2.x * w.x + h2.y * w.y;
        w = *(const float2*)(Wc  + 0 * DIM + lane * 2); p[4] = x2.x * w.x + x2.y * w.y;
        w = *(const float2*)(Wc  + 1 * DIM + lane * 2); p[5] = x2.x * w.x + x2.y * w.y;
        w = *(const float2*)(Wc  + 2 * DIM + lane * 2); p[6] = x2.x * w.x + x2.y * w.y;
    }
#pragma unroll
    for (int i = 0; i < 7; ++i) {
        float v = p[i];
#pragma unroll
        for (int o = 32; o > 0; o >>= 1) v += __shfl_xor(v, o);
        p[i] = v;
    }
    if (lane == 0) {
        albuf[wid * 2 + 0] = p[0] + alb[0];
        albuf[wid * 2 + 1] = p[1] + alb[1];
        arbuf[wid * 2 + 0] = p[2] + arb[0];
        arbuf[wid * 2 + 1] = p[3] + arb[1];
        float c0 = p[4] + bc[0], c1 = p[5] + bc[1], c2 = p[6] + bc[2];
        float mx = fmaxf(c0, fmaxf(c1, c2));
        float e0 = __expf(c0 - mx), e1 = __expf(c1 - mx), e2 = __expf(c2 - mx);
        float s = e0 + e1 + e2;
        betab[wid * 3 + 0] = e0 / s;
        betab[wid * 3 + 1] = e1 / s;
        betab[wid * 3 + 2] = e2 / s;
    }
}

// ---------------- K3: degree count, both metapaths concatenated ----------------
__global__ __launch_bounds__(256) void k_count(
    const int* __restrict__ ei1, const int* __restrict__ ei2,
    int* __restrict__ cnt, int n, int e)
{
    int t = blockIdx.x * 256 + threadIdx.x;
    if (t < e)          atomicAdd(&cnt[ei1[t]], 1);
    else if (t < 2 * e) atomicAdd(&cnt[n + ei2[t - e]], 1);
}

// ---------------- K4: exclusive scan over 2N counts (2-level) ----------------
__global__ __launch_bounds__(256) void k_scan1(
    const int* __restrict__ cnt, int* __restrict__ excl,
    int* __restrict__ bsum, int n2)
{
    __shared__ int sh[256];
    int t = threadIdx.x;
    int base = blockIdx.x * 1024 + t * 4;
    int v0 = (base + 0 < n2) ? cnt[base + 0] : 0;
    int v1 = (base + 1 < n2) ? cnt[base + 1] : 0;
    int v2 = (base + 2 < n2) ? cnt[base + 2] : 0;
    int v3 = (base + 3 < n2) ? cnt[base + 3] : 0;
    int s1 = v0 + v1, s2 = s1 + v2, s3 = s2 + v3;
    sh[t] = s3;
    __syncthreads();
    for (int off = 1; off < 256; off <<= 1) {
        int a = (t >= off) ? sh[t - off] : 0;
        __syncthreads();
        sh[t] += a;
        __syncthreads();
    }
    int eb = sh[t] - s3;
    if (t == 255) bsum[blockIdx.x] = sh[255];
    if (base + 0 < n2) excl[base + 0] = eb;
    if (base + 1 < n2) excl[base + 1] = eb + v0;
    if (base + 2 < n2) excl[base + 2] = eb + s1;
    if (base + 3 < n2) excl[base + 3] = eb + s2;
}

__global__ __launch_bounds__(256) void k_scan2(int* __restrict__ bsum, int nb)
{
    __shared__ int sh[256];
    int t = threadIdx.x;
    int v = (t < nb) ? bsum[t] : 0;
    sh[t] = v;
    __syncthreads();
    for (int off = 1; off < 256; off <<= 1) {
        int a = (t >= off) ? sh[t - off] : 0;
        __syncthreads();
        sh[t] += a;
        __syncthreads();
    }
    if (t < nb) bsum[t] = sh[t] - v;
}

__global__ __launch_bounds__(256) void k_scan3(
    int* __restrict__ rp, const int* __restrict__ bsum,
    int* __restrict__ woff, int n2, int etot)
{
    int i = blockIdx.x * 256 + threadIdx.x;
    if (i < n2) {
        int r = rp[i] + bsum[i >> 10];
        rp[i]   = r;
        woff[i] = r;
    }
    if (i == 0) rp[n2] = etot;
}

// ---------------- K5: CSR fill, packed {src, exp(logit)} ----------------
__global__ __launch_bounds__(256) void k_fill(
    const int* __restrict__ ei1, const int* __restrict__ ei2,
    const float* __restrict__ al, const float* __restrict__ ar,
    const float* __restrict__ alpha,
    int* __restrict__ woff, int2* __restrict__ pairs, int n, int e)
{
    int t = blockIdx.x * 256 + threadIdx.x;
    if (t >= 2 * e) return;
    int m = (t >= e);
    const int* ei = m ? ei2 : ei1;
    int tt = t - m * e;
    int d = ei[tt];
    int s = ei[e + tt];
    float ex = __expf(alpha[m] * (al[s * 2 + m] + ar[d * 2 + m]));
    int pos = atomicAdd(&woff[d + m * n], 1);
    pairs[pos] = make_int2(s, __float_as_int(ex));
}

// ---------------- K6: fused gather (bf16) + self + relu ----------------
__global__ __launch_bounds__(256) void k_gather(
    const float* __restrict__ h, const unsigned* __restrict__ h2,
    const float* __restrict__ betab, const int* __restrict__ rp,
    const int2* __restrict__ pairs, float* __restrict__ out, int n)
{
    int wid  = blockIdx.x * 4 + (threadIdx.x >> 6);
    if (wid >= n) return;
    int lane = threadIdx.x & 63;

    float b0 = betab[wid * 3 + 0];
    float b1 = betab[wid * 3 + 1];
    float b2 = betab[wid * 3 + 2];

    float2 acc;
    {
        const float2 hv = *(const float2*)(h + (size_t)wid * DIM + lane * 2);
        acc.x = b2 * hv.x;
        acc.y = b2 * hv.y;
    }

#pragma unroll
    for (int m = 0; m < 2; ++m) {
        int s0 = rp[m * n + wid];
        int s1 = rp[m * n + wid + 1];
        float bm = m ? b1 : b0;

        float sum = 0.0f;
        float2 a = {0.0f, 0.0f};
        for (int j = s0; j < s1; ++j) {
            int2 pr = pairs[j];
            float ex = __int_as_float(pr.y);
            sum += ex;
            unsigned u = h2[(size_t)pr.x * 64 + lane];
            a.x = fmaf(ex, __uint_as_float(u << 16), a.x);
            a.y = fmaf(ex, __uint_as_float(u & 0xFFFF0000u), a.y);
        }
        float sc = bm / (sum + 1e-16f);
        acc.x = fmaf(sc, a.x, acc.x);
        acc.y = fmaf(sc, a.y, acc.y);
    }

    float2 o;
    o.x = fmaxf(acc.x, 0.0f);
    o.y = fmaxf(acc.y, 0.0f);
    *(float2*)(out + (size_t)wid * DIM + lane * 2) = o;
}

extern "C" void kernel_launch(void* const* d_in, const int* in_sizes, int n_in,
                              void* d_out, int out_size, void* d_ws, size_t ws_size,
                              hipStream_t stream)
{
    const float* x     = (const float*)d_in[0];
    const int*   ei1   = (const int*)d_in[1];
    const int*   ei2   = (const int*)d_in[2];
    const float* W_lin = (const float*)d_in[3];
    const float* b_lin = (const float*)d_in[4];
    const float* W_cv  = (const float*)d_in[5];
    const float* b_cv  = (const float*)d_in[6];
    const float* alw   = (const float*)d_in[7];
    const float* alb   = (const float*)d_in[8];
    const float* arw   = (const float*)d_in[9];
    const float* arb   = (const float*)d_in[10];
    const float* alpha = (const float*)d_in[11];

    const int N  = in_sizes[0] / DIM;
    const int E  = in_sizes[1] / 2;
    const int N2 = 2 * N;

    float* out = (float*)d_out;

    // workspace layout (4-byte units)
    float*    h     = (float*)d_ws;                    // N*128
    unsigned* h2    = (unsigned*)(h + (size_t)N * DIM);// N*64
    float*    albuf = (float*)(h2 + (size_t)N * 64);   // 2N
    float*    arbuf = albuf + (size_t)2 * N;           // 2N
    float*    betab = arbuf + (size_t)2 * N;           // 3N
    int*      rp    = (int*)(betab + (size_t)3 * N);   // 2N+2 (padded even)
    int*      woff  = rp + (N2 + 2);                   // 2N
    int*      bsum  = woff + N2;                       // 256
    int2*     pairs = (int2*)(bsum + 256);             // 2E int2

    const int nb = (N2 + 1023) / 1024;                 // 196 for N=100000

    hipMemsetAsync(woff, 0, (size_t)N2 * sizeof(int), stream);

    k_gemm_h<<<(N + 63) / 64, 256, 0, stream>>>(x, W_lin, b_lin, h, h2, N);

    k_node_vec<<<(N + 3) / 4, 256, 0, stream>>>(x, h, W_cv, b_cv, alw, alb,
                                                arw, arb, albuf, arbuf, betab, N);

    k_count<<<(2 * E + 255) / 256, 256, 0, stream>>>(ei1, ei2, woff, N, E);

    k_scan1<<<nb, 256, 0, stream>>>(woff, rp, bsum, N2);
    k_scan2<<<1, 256, 0, stream>>>(bsum, nb);
    k_scan3<<<(N2 + 255) / 256, 256, 0, stream>>>(rp, bsum, woff, N2, 2 * E);

    k_fill<<<(2 * E + 255) / 256, 256, 0, stream>>>(ei1, ei2, albuf, arbuf,
                                                    alpha, woff, pairs, N, E);

    k_gather<<<(N + 3) / 4, 256, 0, stream>>>(h, h2, betab, rp, pairs, out, N);
}

// Round 4
// 499.347 us; speedup vs baseline: 5.9648x; 1.5080x over previous
//
#include <hip/hip_runtime.h>

#define DIM 128

__device__ __forceinline__ unsigned bfbits(float f) {
    unsigned u = __float_as_uint(f);
    return (u + 0x7FFFu + ((u >> 16) & 1u)) >> 16;   // RNE bf16
}
__device__ __forceinline__ float bflo(unsigned u) { return __uint_as_float(u << 16); }
__device__ __forceinline__ float bfhi(unsigned u) { return __uint_as_float(u & 0xFFFF0000u); }

// ---------------- K1: h = x @ W_lin^T + b_lin (+ bf16 copy h2) ----------------
__global__ __launch_bounds__(256) void k_gemm_h(
    const float* __restrict__ x, const float* __restrict__ W,
    const float* __restrict__ b, float* __restrict__ h,
    unsigned* __restrict__ h2, int n)
{
    __shared__ float wT[128][132];
    __shared__ float xT[128][68];
    const int tid  = threadIdx.x;
    const int row0 = blockIdx.x * 64;

    for (int i = 0; i < 64; ++i) {
        int g = tid + i * 256;
        wT[g & 127][g >> 7] = W[g];
    }
    for (int i = 0; i < 32; ++i) {
        int g = tid + i * 256;
        int r = g >> 7, k = g & 127;
        int row = row0 + r;
        xT[k][r] = (row < n) ? x[(size_t)row * DIM + k] : 0.0f;
    }
    __syncthreads();

    const int c = (tid & 15) * 8;
    const int r = (tid >> 4) * 4;

    float acc[4][8];
#pragma unroll
    for (int i = 0; i < 4; ++i)
#pragma unroll
        for (int j = 0; j < 8; ++j) acc[i][j] = 0.0f;

#pragma unroll 4
    for (int k = 0; k < 128; ++k) {
        const float4 xv = *(const float4*)&xT[k][r];
        const float4 wa = *(const float4*)&wT[k][c];
        const float4 wb = *(const float4*)&wT[k][c + 4];
        const float xr[4] = {xv.x, xv.y, xv.z, xv.w};
        const float wc[8] = {wa.x, wa.y, wa.z, wa.w, wb.x, wb.y, wb.z, wb.w};
#pragma unroll
        for (int i = 0; i < 4; ++i)
#pragma unroll
            for (int j = 0; j < 8; ++j)
                acc[i][j] = fmaf(xr[i], wc[j], acc[i][j]);
    }

    const float4 b0 = *(const float4*)&b[c];
    const float4 b1 = *(const float4*)&b[c + 4];
#pragma unroll
    for (int i = 0; i < 4; ++i) {
        int row = row0 + r + i;
        if (row < n) {
            float4 o0 = {acc[i][0] + b0.x, acc[i][1] + b0.y,
                         acc[i][2] + b0.z, acc[i][3] + b0.w};
            float4 o1 = {acc[i][4] + b1.x, acc[i][5] + b1.y,
                         acc[i][6] + b1.z, acc[i][7] + b1.w};
            *(float4*)&h[(size_t)row * DIM + c]     = o0;
            *(float4*)&h[(size_t)row * DIM + c + 4] = o1;
            uint4 p;
            p.x = bfbits(o0.x) | (bfbits(o0.y) << 16);
            p.y = bfbits(o0.z) | (bfbits(o0.w) << 16);
            p.z = bfbits(o1.x) | (bfbits(o1.y) << 16);
            p.w = bfbits(o1.z) | (bfbits(o1.w) << 16);
            *(uint4*)&h2[(size_t)row * 64 + (c >> 1)] = p;
        }
    }
}

// ---------------- K2: per-node al, ar, beta ----------------
__global__ __launch_bounds__(256) void k_node_vec(
    const float* __restrict__ x, const float* __restrict__ h,
    const float* __restrict__ Wc, const float* __restrict__ bc,
    const float* __restrict__ alw, const float* __restrict__ alb,
    const float* __restrict__ arw, const float* __restrict__ arb,
    float* __restrict__ albuf, float* __restrict__ arbuf,
    float* __restrict__ betab, int n)
{
    int wid  = blockIdx.x * 4 + (threadIdx.x >> 6);
    int lane = threadIdx.x & 63;
    if (wid >= n) return;

    const float2 x2 = *(const float2*)(x + (size_t)wid * DIM + lane * 2);
    const float2 h2 = *(const float2*)(h + (size_t)wid * DIM + lane * 2);

    float p[7];
    {
        float2 w;
        w = *(const float2*)(alw + 0 * DIM + lane * 2); p[0] = h2.x * w.x + h2.y * w.y;
        w = *(const float2*)(alw + 1 * DIM + lane * 2); p[1] = h2.x * w.x + h2.y * w.y;
        w = *(const float2*)(arw + 0 * DIM + lane * 2); p[2] = h2.x * w.x + h2.y * w.y;
        w = *(const float2*)(arw + 1 * DIM + lane * 2); p[3] = h2.x * w.x + h2.y * w.y;
        w = *(const float2*)(Wc  + 0 * DIM + lane * 2); p[4] = x2.x * w.x + x2.y * w.y;
        w = *(const float2*)(Wc  + 1 * DIM + lane * 2); p[5] = x2.x * w.x + x2.y * w.y;
        w = *(const float2*)(Wc  + 2 * DIM + lane * 2); p[6] = x2.x * w.x + x2.y * w.y;
    }
#pragma unroll
    for (int i = 0; i < 7; ++i) {
        float v = p[i];
#pragma unroll
        for (int o = 32; o > 0; o >>= 1) v += __shfl_xor(v, o);
        p[i] = v;
    }
    if (lane == 0) {
        albuf[wid * 2 + 0] = p[0] + alb[0];
        albuf[wid * 2 + 1] = p[1] + alb[1];
        arbuf[wid * 2 + 0] = p[2] + arb[0];
        arbuf[wid * 2 + 1] = p[3] + arb[1];
        float c0 = p[4] + bc[0], c1 = p[5] + bc[1], c2 = p[6] + bc[2];
        float mx = fmaxf(c0, fmaxf(c1, c2));
        float e0 = __expf(c0 - mx), e1 = __expf(c1 - mx), e2 = __expf(c2 - mx);
        float s = e0 + e1 + e2;
        betab[wid * 3 + 0] = e0 / s;
        betab[wid * 3 + 1] = e1 / s;
        betab[wid * 3 + 2] = e2 / s;
    }
}

// ---------------- K3: degree count + per-edge rank ----------------
__global__ __launch_bounds__(256) void k_count(
    const int* __restrict__ ei1, const int* __restrict__ ei2,
    int* __restrict__ cnt, int* __restrict__ ph, int n, int e)
{
    int t = blockIdx.x * 256 + threadIdx.x;
    if (t < e)          ph[t] = atomicAdd(&cnt[ei1[t]], 1);
    else if (t < 2 * e) ph[t] = atomicAdd(&cnt[n + ei2[t - e]], 1);
}

// ---------------- K4: exclusive scan over 2N counts (2-level) ----------------
__global__ __launch_bounds__(256) void k_scan1(
    const int* __restrict__ cnt, int* __restrict__ excl,
    int* __restrict__ bsum, int n2)
{
    __shared__ int sh[256];
    int t = threadIdx.x;
    int base = blockIdx.x * 1024 + t * 4;
    int v0 = (base + 0 < n2) ? cnt[base + 0] : 0;
    int v1 = (base + 1 < n2) ? cnt[base + 1] : 0;
    int v2 = (base + 2 < n2) ? cnt[base + 2] : 0;
    int v3 = (base + 3 < n2) ? cnt[base + 3] : 0;
    int s1 = v0 + v1, s2 = s1 + v2, s3 = s2 + v3;
    sh[t] = s3;
    __syncthreads();
    for (int off = 1; off < 256; off <<= 1) {
        int a = (t >= off) ? sh[t - off] : 0;
        __syncthreads();
        sh[t] += a;
        __syncthreads();
    }
    int eb = sh[t] - s3;
    if (t == 255) bsum[blockIdx.x] = sh[255];
    if (base + 0 < n2) excl[base + 0] = eb;
    if (base + 1 < n2) excl[base + 1] = eb + v0;
    if (base + 2 < n2) excl[base + 2] = eb + s1;
    if (base + 3 < n2) excl[base + 3] = eb + s2;
}

__global__ __launch_bounds__(256) void k_scan2(int* __restrict__ bsum, int nb)
{
    __shared__ int sh[256];
    int t = threadIdx.x;
    int v = (t < nb) ? bsum[t] : 0;
    sh[t] = v;
    __syncthreads();
    for (int off = 1; off < 256; off <<= 1) {
        int a = (t >= off) ? sh[t - off] : 0;
        __syncthreads();
        sh[t] += a;
        __syncthreads();
    }
    if (t < nb) bsum[t] = sh[t] - v;
}

__global__ __launch_bounds__(256) void k_scan3(
    int* __restrict__ rp, const int* __restrict__ bsum, int n2, int etot)
{
    int i = blockIdx.x * 256 + threadIdx.x;
    if (i < n2) rp[i] += bsum[i >> 10];
    if (i == 0) rp[n2] = etot;
}

// ---------------- K5: CSR fill (src only, no atomics) ----------------
__global__ __launch_bounds__(256) void k_fill(
    const int* __restrict__ ei1, const int* __restrict__ ei2,
    const int* __restrict__ rp, const int* __restrict__ ph,
    int* __restrict__ srcs, int n, int e)
{
    int t = blockIdx.x * 256 + threadIdx.x;
    if (t >= 2 * e) return;
    int m = (t >= e);
    const int* ei = m ? ei2 : ei1;
    int tt = t - m * e;
    int d = ei[tt] + m * n;
    int s = ei[e + tt];
    srcs[rp[d] + ph[t]] = s;
}

// ---------------- K6: fused gather (bf16, pipelined) + self + relu ----------------
__global__ __launch_bounds__(256) void k_gather(
    const float* __restrict__ h, const unsigned* __restrict__ h2,
    const float* __restrict__ albuf, const float* __restrict__ arbuf,
    const float* __restrict__ betab, const float* __restrict__ alpha,
    const int* __restrict__ rp, const int* __restrict__ srcs,
    float* __restrict__ out, int n)
{
    int wid  = blockIdx.x * 4 + (threadIdx.x >> 6);
    if (wid >= n) return;
    int lane = threadIdx.x & 63;

    float b0 = betab[wid * 3 + 0];
    float b1 = betab[wid * 3 + 1];
    float b2 = betab[wid * 3 + 2];

    float2 acc;
    {
        const float2 hv = *(const float2*)(h + (size_t)wid * DIM + lane * 2);
        acc.x = b2 * hv.x;
        acc.y = b2 * hv.y;
    }

#pragma unroll
    for (int m = 0; m < 2; ++m) {
        const int s0 = rp[m * n + wid];
        const int s1 = rp[m * n + wid + 1];
        const float am  = alpha[m];
        const float arv = arbuf[wid * 2 + m];
        const float bm  = m ? b1 : b0;

        float sum = 0.0f;
        float2 a = {0.0f, 0.0f};

        for (int base = s0; base < s1; base += 64) {
            const int cnt = min(64, s1 - base);

            // batch phase: lane j owns edge base+j
            int   src = 0;
            float ex  = 0.0f;
            if (lane < cnt) {
                src = srcs[base + lane];
                ex  = __expf(am * (albuf[src * 2 + m] + arv));
            }
            {   // denom
                float t = ex;
#pragma unroll
                for (int o = 32; o > 0; o >>= 1) t += __shfl_xor(t, o);
                sum += t;
            }

            // accumulate, 4 edges in flight
            int j = 0;
            for (; j + 4 <= cnt; j += 4) {
                int   sA = __shfl(src, j + 0), sB = __shfl(src, j + 1);
                int   sC = __shfl(src, j + 2), sD = __shfl(src, j + 3);
                float wA = __shfl(ex,  j + 0), wB = __shfl(ex,  j + 1);
                float wC = __shfl(ex,  j + 2), wD = __shfl(ex,  j + 3);
                unsigned uA = h2[(size_t)sA * 64 + lane];
                unsigned uB = h2[(size_t)sB * 64 + lane];
                unsigned uC = h2[(size_t)sC * 64 + lane];
                unsigned uD = h2[(size_t)sD * 64 + lane];
                a.x = fmaf(wA, bflo(uA), a.x); a.y = fmaf(wA, bfhi(uA), a.y);
                a.x = fmaf(wB, bflo(uB), a.x); a.y = fmaf(wB, bfhi(uB), a.y);
                a.x = fmaf(wC, bflo(uC), a.x); a.y = fmaf(wC, bfhi(uC), a.y);
                a.x = fmaf(wD, bflo(uD), a.x); a.y = fmaf(wD, bfhi(uD), a.y);
            }
            for (; j < cnt; ++j) {
                int   sA = __shfl(src, j);
                float wA = __shfl(ex,  j);
                unsigned uA = h2[(size_t)sA * 64 + lane];
                a.x = fmaf(wA, bflo(uA), a.x);
                a.y = fmaf(wA, bfhi(uA), a.y);
            }
        }

        float sc = bm / (sum + 1e-16f);
        acc.x = fmaf(sc, a.x, acc.x);
        acc.y = fmaf(sc, a.y, acc.y);
    }

    float2 o;
    o.x = fmaxf(acc.x, 0.0f);
    o.y = fmaxf(acc.y, 0.0f);
    *(float2*)(out + (size_t)wid * DIM + lane * 2) = o;
}

extern "C" void kernel_launch(void* const* d_in, const int* in_sizes, int n_in,
                              void* d_out, int out_size, void* d_ws, size_t ws_size,
                              hipStream_t stream)
{
    const float* x     = (const float*)d_in[0];
    const int*   ei1   = (const int*)d_in[1];
    const int*   ei2   = (const int*)d_in[2];
    const float* W_lin = (const float*)d_in[3];
    const float* b_lin = (const float*)d_in[4];
    const float* W_cv  = (const float*)d_in[5];
    const float* b_cv  = (const float*)d_in[6];
    const float* alw   = (const float*)d_in[7];
    const float* alb   = (const float*)d_in[8];
    const float* arw   = (const float*)d_in[9];
    const float* arb   = (const float*)d_in[10];
    const float* alpha = (const float*)d_in[11];

    const int N  = in_sizes[0] / DIM;
    const int E  = in_sizes[1] / 2;
    const int N2 = 2 * N;

    float* out = (float*)d_out;

    // workspace layout (4-byte units)
    float*    h     = (float*)d_ws;                     // N*128
    unsigned* h2    = (unsigned*)(h + (size_t)N * DIM); // N*64
    float*    albuf = (float*)(h2 + (size_t)N * 64);    // 2N
    float*    arbuf = albuf + (size_t)2 * N;            // 2N
    float*    betab = arbuf + (size_t)2 * N;            // 3N
    int*      rp    = (int*)(betab + (size_t)3 * N);    // 2N+2
    int*      cnt   = rp + (N2 + 2);                    // 2N
    int*      bsum  = cnt + N2;                         // 256
    int*      ph    = bsum + 256;                       // 2E
    int*      srcs  = ph + (size_t)2 * E;               // 2E

    const int nb = (N2 + 1023) / 1024;

    hipMemsetAsync(cnt, 0, (size_t)N2 * sizeof(int), stream);

    k_gemm_h<<<(N + 63) / 64, 256, 0, stream>>>(x, W_lin, b_lin, h, h2, N);

    k_node_vec<<<(N + 3) / 4, 256, 0, stream>>>(x, h, W_cv, b_cv, alw, alb,
                                                arw, arb, albuf, arbuf, betab, N);

    k_count<<<(2 * E + 255) / 256, 256, 0, stream>>>(ei1, ei2, cnt, ph, N, E);

    k_scan1<<<nb, 256, 0, stream>>>(cnt, rp, bsum, N2);
    k_scan2<<<1, 256, 0, stream>>>(bsum, nb);
    k_scan3<<<(N2 + 255) / 256, 256, 0, stream>>>(rp, bsum, N2, 2 * E);

    k_fill<<<(2 * E + 255) / 256, 256, 0, stream>>>(ei1, ei2, rp, ph, srcs, N, E);

    k_gather<<<(N + 3) / 4, 256, 0, stream>>>(h, h2, albuf, arbuf, betab, alpha,
                                              rp, srcs, out, N);
}

// Round 5
// 410.777 us; speedup vs baseline: 7.2509x; 1.2156x over previous
//
#include <hip/hip_runtime.h>

#define DIM 128

typedef __attribute__((ext_vector_type(8))) short bf16x8;
typedef __attribute__((ext_vector_type(4))) float f32x4;

__device__ __forceinline__ unsigned bfbits(float f) {
    unsigned u = __float_as_uint(f);
    return (u + 0x7FFFu + ((u >> 16) & 1u)) >> 16;   // RNE bf16
}
__device__ __forceinline__ float bflo(unsigned u) { return __uint_as_float(u << 16); }
__device__ __forceinline__ float bfhi(unsigned u) { return __uint_as_float(u & 0xFFFF0000u); }

// ---------------- K1: h = x @ W_lin^T + b_lin via MFMA (+ bf16 copy h2) ------
// 4 waves/block, 64 rows x 128 cols per block. W,x staged as bf16 in LDS
// (row stride 136 shorts = 272 B -> 2-way bank pattern, free).
__global__ __launch_bounds__(256) void k_gemm_h(
    const float* __restrict__ x, const float* __restrict__ W,
    const float* __restrict__ b, float* __restrict__ h,
    unsigned short* __restrict__ h2u, int n)
{
    __shared__ short wlds[128 * 136];
    __shared__ short xlds[64 * 136];
    const int tid  = threadIdx.x;
    const int row0 = blockIdx.x * 64;

    // stage W (128x128 fp32 -> bf16 LDS): 2 threads per row
    {
        const int j = tid >> 1, half = tid & 1;
        const float4* W4 = (const float4*)W;
#pragma unroll
        for (int i = 0; i < 8; ++i) {
            float4 fa = W4[j * 32 + half * 16 + i * 2];
            float4 fb = W4[j * 32 + half * 16 + i * 2 + 1];
            uint4 p;
            p.x = bfbits(fa.x) | (bfbits(fa.y) << 16);
            p.y = bfbits(fa.z) | (bfbits(fa.w) << 16);
            p.z = bfbits(fb.x) | (bfbits(fb.y) << 16);
            p.w = bfbits(fb.z) | (bfbits(fb.w) << 16);
            *(uint4*)&wlds[j * 136 + half * 64 + i * 8] = p;
        }
    }
    // stage x rows row0..row0+63 -> bf16 LDS: 4 threads per row
    {
        const int r = tid >> 2, q = tid & 3;
        const int row = min(row0 + r, n - 1);
        const float4* x4 = (const float4*)x;
#pragma unroll
        for (int i = 0; i < 4; ++i) {
            float4 fa = x4[(size_t)row * 32 + q * 8 + i * 2];
            float4 fb = x4[(size_t)row * 32 + q * 8 + i * 2 + 1];
            uint4 p;
            p.x = bfbits(fa.x) | (bfbits(fa.y) << 16);
            p.y = bfbits(fa.z) | (bfbits(fa.w) << 16);
            p.z = bfbits(fb.x) | (bfbits(fb.y) << 16);
            p.w = bfbits(fb.z) | (bfbits(fb.w) << 16);
            *(uint4*)&xlds[r * 136 + q * 32 + i * 8] = p;
        }
    }
    __syncthreads();

    const int wv = tid >> 6, lane = tid & 63;
    const int lr = lane & 15, lg = lane >> 4;

    f32x4 acc[8];
#pragma unroll
    for (int c = 0; c < 8; ++c) acc[c] = (f32x4){0.f, 0.f, 0.f, 0.f};

#pragma unroll
    for (int ks = 0; ks < 4; ++ks) {
        bf16x8 a = *(const bf16x8*)&xlds[(wv * 16 + lr) * 136 + ks * 32 + lg * 8];
#pragma unroll
        for (int c = 0; c < 8; ++c) {
            bf16x8 bb = *(const bf16x8*)&wlds[(c * 16 + lr) * 136 + ks * 32 + lg * 8];
            acc[c] = __builtin_amdgcn_mfma_f32_16x16x32_bf16(a, bb, acc[c], 0, 0, 0);
        }
    }

    // epilogue: C/D layout col=lane&15, row=(lane>>4)*4+reg  [m89-verified]
    const int rbase = row0 + wv * 16 + lg * 4;
#pragma unroll
    for (int c = 0; c < 8; ++c) {
        const int col = c * 16 + lr;
        const float bc = b[col];
#pragma unroll
        for (int r = 0; r < 4; ++r) {
            const int row = rbase + r;
            if (row < n) {
                float v = acc[c][r] + bc;
                h[(size_t)row * DIM + col]   = v;
                h2u[(size_t)row * DIM + col] = (unsigned short)bfbits(v);
            }
        }
    }
}

// ---------------- K2: per-node al, ar, beta ----------------
__global__ __launch_bounds__(256) void k_node_vec(
    const float* __restrict__ x, const float* __restrict__ h,
    const float* __restrict__ Wc, const float* __restrict__ bc,
    const float* __restrict__ alw, const float* __restrict__ alb,
    const float* __restrict__ arw, const float* __restrict__ arb,
    float* __restrict__ albuf, float* __restrict__ arbuf,
    float* __restrict__ betab, int n)
{
    int wid  = blockIdx.x * 4 + (threadIdx.x >> 6);
    int lane = threadIdx.x & 63;
    if (wid >= n) return;

    const float2 x2 = *(const float2*)(x + (size_t)wid * DIM + lane * 2);
    const float2 h2 = *(const float2*)(h + (size_t)wid * DIM + lane * 2);

    float p[7];
    {
        float2 w;
        w = *(const float2*)(alw + 0 * DIM + lane * 2); p[0] = h2.x * w.x + h2.y * w.y;
        w = *(const float2*)(alw + 1 * DIM + lane * 2); p[1] = h2.x * w.x + h2.y * w.y;
        w = *(const float2*)(arw + 0 * DIM + lane * 2); p[2] = h2.x * w.x + h2.y * w.y;
        w = *(const float2*)(arw + 1 * DIM + lane * 2); p[3] = h2.x * w.x + h2.y * w.y;
        w = *(const float2*)(Wc  + 0 * DIM + lane * 2); p[4] = x2.x * w.x + x2.y * w.y;
        w = *(const float2*)(Wc  + 1 * DIM + lane * 2); p[5] = x2.x * w.x + x2.y * w.y;
        w = *(const float2*)(Wc  + 2 * DIM + lane * 2); p[6] = x2.x * w.x + x2.y * w.y;
    }
#pragma unroll
    for (int i = 0; i < 7; ++i) {
        float v = p[i];
#pragma unroll
        for (int o = 32; o > 0; o >>= 1) v += __shfl_xor(v, o);
        p[i] = v;
    }
    if (lane == 0) {
        albuf[wid * 2 + 0] = p[0] + alb[0];
        albuf[wid * 2 + 1] = p[1] + alb[1];
        arbuf[wid * 2 + 0] = p[2] + arb[0];
        arbuf[wid * 2 + 1] = p[3] + arb[1];
        float c0 = p[4] + bc[0], c1 = p[5] + bc[1], c2 = p[6] + bc[2];
        float mx = fmaxf(c0, fmaxf(c1, c2));
        float e0 = __expf(c0 - mx), e1 = __expf(c1 - mx), e2 = __expf(c2 - mx);
        float s = e0 + e1 + e2;
        betab[wid * 3 + 0] = e0 / s;
        betab[wid * 3 + 1] = e1 / s;
        betab[wid * 3 + 2] = e2 / s;
    }
}

// ---------------- K3: degree count + per-edge rank ----------------
__global__ __launch_bounds__(256) void k_count(
    const int* __restrict__ ei1, const int* __restrict__ ei2,
    int* __restrict__ cnt, int* __restrict__ ph, int n, int e)
{
    int t = blockIdx.x * 256 + threadIdx.x;
    if (t < e)          ph[t] = atomicAdd(&cnt[ei1[t]], 1);
    else if (t < 2 * e) ph[t] = atomicAdd(&cnt[n + ei2[t - e]], 1);
}

// ---------------- K4: exclusive scan over 2N counts (2-level) ----------------
__global__ __launch_bounds__(256) void k_scan1(
    const int* __restrict__ cnt, int* __restrict__ excl,
    int* __restrict__ bsum, int n2)
{
    __shared__ int sh[256];
    int t = threadIdx.x;
    int base = blockIdx.x * 1024 + t * 4;
    int v0 = (base + 0 < n2) ? cnt[base + 0] : 0;
    int v1 = (base + 1 < n2) ? cnt[base + 1] : 0;
    int v2 = (base + 2 < n2) ? cnt[base + 2] : 0;
    int v3 = (base + 3 < n2) ? cnt[base + 3] : 0;
    int s1 = v0 + v1, s2 = s1 + v2, s3 = s2 + v3;
    sh[t] = s3;
    __syncthreads();
    for (int off = 1; off < 256; off <<= 1) {
        int a = (t >= off) ? sh[t - off] : 0;
        __syncthreads();
        sh[t] += a;
        __syncthreads();
    }
    int eb = sh[t] - s3;
    if (t == 255) bsum[blockIdx.x] = sh[255];
    if (base + 0 < n2) excl[base + 0] = eb;
    if (base + 1 < n2) excl[base + 1] = eb + v0;
    if (base + 2 < n2) excl[base + 2] = eb + s1;
    if (base + 3 < n2) excl[base + 3] = eb + s2;
}

__global__ __launch_bounds__(256) void k_scan2(int* __restrict__ bsum, int nb)
{
    __shared__ int sh[256];
    int t = threadIdx.x;
    int v = (t < nb) ? bsum[t] : 0;
    sh[t] = v;
    __syncthreads();
    for (int off = 1; off < 256; off <<= 1) {
        int a = (t >= off) ? sh[t - off] : 0;
        __syncthreads();
        sh[t] += a;
        __syncthreads();
    }
    if (t < nb) bsum[t] = sh[t] - v;
}

__global__ __launch_bounds__(256) void k_scan3(
    int* __restrict__ rp, const int* __restrict__ bsum, int n2, int etot)
{
    int i = blockIdx.x * 256 + threadIdx.x;
    if (i < n2) rp[i] += bsum[i >> 10];
    if (i == 0) rp[n2] = etot;
}

// ---------------- K5: CSR fill (src only, no atomics) ----------------
__global__ __launch_bounds__(256) void k_fill(
    const int* __restrict__ ei1, const int* __restrict__ ei2,
    const int* __restrict__ rp, const int* __restrict__ ph,
    int* __restrict__ srcs, int n, int e)
{
    int t = blockIdx.x * 256 + threadIdx.x;
    if (t >= 2 * e) return;
    int m = (t >= e);
    const int* ei = m ? ei2 : ei1;
    int tt = t - m * e;
    int d = ei[tt] + m * n;
    int s = ei[e + tt];
    srcs[rp[d] + ph[t]] = s;
}

// ---------------- K6: fused gather (bf16, pipelined) + self + relu ----------------
__global__ __launch_bounds__(256) void k_gather(
    const float* __restrict__ h, const unsigned* __restrict__ h2,
    const float* __restrict__ albuf, const float* __restrict__ arbuf,
    const float* __restrict__ betab, const float* __restrict__ alpha,
    const int* __restrict__ rp, const int* __restrict__ srcs,
    float* __restrict__ out, int n)
{
    int wid  = blockIdx.x * 4 + (threadIdx.x >> 6);
    if (wid >= n) return;
    int lane = threadIdx.x & 63;

    float b0 = betab[wid * 3 + 0];
    float b1 = betab[wid * 3 + 1];
    float b2 = betab[wid * 3 + 2];

    float2 acc;
    {
        const float2 hv = *(const float2*)(h + (size_t)wid * DIM + lane * 2);
        acc.x = b2 * hv.x;
        acc.y = b2 * hv.y;
    }

#pragma unroll
    for (int m = 0; m < 2; ++m) {
        const int s0 = rp[m * n + wid];
        const int s1 = rp[m * n + wid + 1];
        const float am  = alpha[m];
        const float arv = arbuf[wid * 2 + m];
        const float bm  = m ? b1 : b0;

        float sum = 0.0f;
        float2 a = {0.0f, 0.0f};

        for (int base = s0; base < s1; base += 64) {
            const int cnt = min(64, s1 - base);

            int   src = 0;
            float ex  = 0.0f;
            if (lane < cnt) {
                src = srcs[base + lane];
                ex  = __expf(am * (albuf[src * 2 + m] + arv));
            }
            {
                float t = ex;
#pragma unroll
                for (int o = 32; o > 0; o >>= 1) t += __shfl_xor(t, o);
                sum += t;
            }

            int j = 0;
            for (; j + 4 <= cnt; j += 4) {
                int   sA = __shfl(src, j + 0), sB = __shfl(src, j + 1);
                int   sC = __shfl(src, j + 2), sD = __shfl(src, j + 3);
                float wA = __shfl(ex,  j + 0), wB = __shfl(ex,  j + 1);
                float wC = __shfl(ex,  j + 2), wD = __shfl(ex,  j + 3);
                unsigned uA = h2[(size_t)sA * 64 + lane];
                unsigned uB = h2[(size_t)sB * 64 + lane];
                unsigned uC = h2[(size_t)sC * 64 + lane];
                unsigned uD = h2[(size_t)sD * 64 + lane];
                a.x = fmaf(wA, bflo(uA), a.x); a.y = fmaf(wA, bfhi(uA), a.y);
                a.x = fmaf(wB, bflo(uB), a.x); a.y = fmaf(wB, bfhi(uB), a.y);
                a.x = fmaf(wC, bflo(uC), a.x); a.y = fmaf(wC, bfhi(uC), a.y);
                a.x = fmaf(wD, bflo(uD), a.x); a.y = fmaf(wD, bfhi(uD), a.y);
            }
            for (; j < cnt; ++j) {
                int   sA = __shfl(src, j);
                float wA = __shfl(ex,  j);
                unsigned uA = h2[(size_t)sA * 64 + lane];
                a.x = fmaf(wA, bflo(uA), a.x);
                a.y = fmaf(wA, bfhi(uA), a.y);
            }
        }

        float sc = bm / (sum + 1e-16f);
        acc.x = fmaf(sc, a.x, acc.x);
        acc.y = fmaf(sc, a.y, acc.y);
    }

    float2 o;
    o.x = fmaxf(acc.x, 0.0f);
    o.y = fmaxf(acc.y, 0.0f);
    *(float2*)(out + (size_t)wid * DIM + lane * 2) = o;
}

extern "C" void kernel_launch(void* const* d_in, const int* in_sizes, int n_in,
                              void* d_out, int out_size, void* d_ws, size_t ws_size,
                              hipStream_t stream)
{
    const float* x     = (const float*)d_in[0];
    const int*   ei1   = (const int*)d_in[1];
    const int*   ei2   = (const int*)d_in[2];
    const float* W_lin = (const float*)d_in[3];
    const float* b_lin = (const float*)d_in[4];
    const float* W_cv  = (const float*)d_in[5];
    const float* b_cv  = (const float*)d_in[6];
    const float* alw   = (const float*)d_in[7];
    const float* alb   = (const float*)d_in[8];
    const float* arw   = (const float*)d_in[9];
    const float* arb   = (const float*)d_in[10];
    const float* alpha = (const float*)d_in[11];

    const int N  = in_sizes[0] / DIM;
    const int E  = in_sizes[1] / 2;
    const int N2 = 2 * N;

    float* out = (float*)d_out;

    // workspace layout (4-byte units)
    float*    h     = (float*)d_ws;                     // N*128
    unsigned* h2    = (unsigned*)(h + (size_t)N * DIM); // N*64
    float*    albuf = (float*)(h2 + (size_t)N * 64);    // 2N
    float*    arbuf = albuf + (size_t)2 * N;            // 2N
    float*    betab = arbuf + (size_t)2 * N;            // 3N
    int*      rp    = (int*)(betab + (size_t)3 * N);    // 2N+2
    int*      cnt   = rp + (N2 + 2);                    // 2N
    int*      bsum  = cnt + N2;                         // 256
    int*      ph    = bsum + 256;                       // 2E
    int*      srcs  = ph + (size_t)2 * E;               // 2E

    const int nb = (N2 + 1023) / 1024;

    hipMemsetAsync(cnt, 0, (size_t)N2 * sizeof(int), stream);

    k_gemm_h<<<(N + 63) / 64, 256, 0, stream>>>(x, W_lin, b_lin, h,
                                                (unsigned short*)h2, N);

    k_node_vec<<<(N + 3) / 4, 256, 0, stream>>>(x, h, W_cv, b_cv, alw, alb,
                                                arw, arb, albuf, arbuf, betab, N);

    k_count<<<(2 * E + 255) / 256, 256, 0, stream>>>(ei1, ei2, cnt, ph, N, E);

    k_scan1<<<nb, 256, 0, stream>>>(cnt, rp, bsum, N2);
    k_scan2<<<1, 256, 0, stream>>>(bsum, nb);
    k_scan3<<<(N2 + 255) / 256, 256, 0, stream>>>(rp, bsum, N2, 2 * E);

    k_fill<<<(2 * E + 255) / 256, 256, 0, stream>>>(ei1, ei2, rp, ph, srcs, N, E);

    k_gather<<<(N + 3) / 4, 256, 0, stream>>>(h, h2, albuf, arbuf, betab, alpha,
                                              rp, srcs, out, N);
}

// Round 6
// 341.142 us; speedup vs baseline: 8.7309x; 1.2041x over previous
//
#include <hip/hip_runtime.h>

#define DIM 128
#define NSL 128          // edge slices per metapath
#define WMAX 25000       // N/4 packed-byte words (N=100000)

typedef __attribute__((ext_vector_type(8))) short bf16x8;
typedef __attribute__((ext_vector_type(4))) float f32x4;

__device__ __forceinline__ unsigned bfbits(float f) {
    unsigned u = __float_as_uint(f);
    return (u + 0x7FFFu + ((u >> 16) & 1u)) >> 16;   // RNE bf16
}
__device__ __forceinline__ float bflo(unsigned u) { return __uint_as_float(u << 16); }
__device__ __forceinline__ float bfhi(unsigned u) { return __uint_as_float(u & 0xFFFF0000u); }

// ---------------- K1: h2(bf16) = x @ W_lin^T + b_lin via MFMA ----------------
__global__ __launch_bounds__(256) void k_gemm_h(
    const float* __restrict__ x, const float* __restrict__ W,
    const float* __restrict__ b, unsigned short* __restrict__ h2u, int n)
{
    __shared__ short wlds[128 * 136];
    __shared__ short xlds[64 * 136];
    const int tid  = threadIdx.x;
    const int row0 = blockIdx.x * 64;

    {
        const int j = tid >> 1, half = tid & 1;
        const float4* W4 = (const float4*)W;
#pragma unroll
        for (int i = 0; i < 8; ++i) {
            float4 fa = W4[j * 32 + half * 16 + i * 2];
            float4 fb = W4[j * 32 + half * 16 + i * 2 + 1];
            uint4 p;
            p.x = bfbits(fa.x) | (bfbits(fa.y) << 16);
            p.y = bfbits(fa.z) | (bfbits(fa.w) << 16);
            p.z = bfbits(fb.x) | (bfbits(fb.y) << 16);
            p.w = bfbits(fb.z) | (bfbits(fb.w) << 16);
            *(uint4*)&wlds[j * 136 + half * 64 + i * 8] = p;
        }
    }
    {
        const int r = tid >> 2, q = tid & 3;
        const int row = min(row0 + r, n - 1);
        const float4* x4 = (const float4*)x;
#pragma unroll
        for (int i = 0; i < 4; ++i) {
            float4 fa = x4[(size_t)row * 32 + q * 8 + i * 2];
            float4 fb = x4[(size_t)row * 32 + q * 8 + i * 2 + 1];
            uint4 p;
            p.x = bfbits(fa.x) | (bfbits(fa.y) << 16);
            p.y = bfbits(fa.z) | (bfbits(fa.w) << 16);
            p.z = bfbits(fb.x) | (bfbits(fb.y) << 16);
            p.w = bfbits(fb.z) | (bfbits(fb.w) << 16);
            *(uint4*)&xlds[r * 136 + q * 32 + i * 8] = p;
        }
    }
    __syncthreads();

    const int wv = tid >> 6, lane = tid & 63;
    const int lr = lane & 15, lg = lane >> 4;

    f32x4 acc[8];
#pragma unroll
    for (int c = 0; c < 8; ++c) acc[c] = (f32x4){0.f, 0.f, 0.f, 0.f};

#pragma unroll
    for (int ks = 0; ks < 4; ++ks) {
        bf16x8 a = *(const bf16x8*)&xlds[(wv * 16 + lr) * 136 + ks * 32 + lg * 8];
#pragma unroll
        for (int c = 0; c < 8; ++c) {
            bf16x8 bb = *(const bf16x8*)&wlds[(c * 16 + lr) * 136 + ks * 32 + lg * 8];
            acc[c] = __builtin_amdgcn_mfma_f32_16x16x32_bf16(a, bb, acc[c], 0, 0, 0);
        }
    }

    const int rbase = row0 + wv * 16 + lg * 4;
#pragma unroll
    for (int c = 0; c < 8; ++c) {
        const int col = c * 16 + lr;
        const float bc = b[col];
#pragma unroll
        for (int r = 0; r < 4; ++r) {
            const int row = rbase + r;
            if (row < n)
                h2u[(size_t)row * DIM + col] = (unsigned short)bfbits(acc[c][r] + bc);
        }
    }
}

// ---------------- K2: per-node al, ar, beta (h from bf16 h2) ----------------
__global__ __launch_bounds__(256) void k_node_vec(
    const float* __restrict__ x, const unsigned* __restrict__ h2,
    const float* __restrict__ Wc, const float* __restrict__ bc,
    const float* __restrict__ alw, const float* __restrict__ alb,
    const float* __restrict__ arw, const float* __restrict__ arb,
    float* __restrict__ albuf, float* __restrict__ arbuf,
    float* __restrict__ betab, int n)
{
    int wid  = blockIdx.x * 4 + (threadIdx.x >> 6);
    int lane = threadIdx.x & 63;
    if (wid >= n) return;

    const float2 x2 = *(const float2*)(x + (size_t)wid * DIM + lane * 2);
    const unsigned hu = h2[(size_t)wid * 64 + lane];
    const float hx = bflo(hu), hy = bfhi(hu);

    float p[7];
    {
        float2 w;
        w = *(const float2*)(alw + 0 * DIM + lane * 2); p[0] = hx * w.x + hy * w.y;
        w = *(const float2*)(alw + 1 * DIM + lane * 2); p[1] = hx * w.x + hy * w.y;
        w = *(const float2*)(arw + 0 * DIM + lane * 2); p[2] = hx * w.x + hy * w.y;
        w = *(const float2*)(arw + 1 * DIM + lane * 2); p[3] = hx * w.x + hy * w.y;
        w = *(const float2*)(Wc  + 0 * DIM + lane * 2); p[4] = x2.x * w.x + x2.y * w.y;
        w = *(const float2*)(Wc  + 1 * DIM + lane * 2); p[5] = x2.x * w.x + x2.y * w.y;
        w = *(const float2*)(Wc  + 2 * DIM + lane * 2); p[6] = x2.x * w.x + x2.y * w.y;
    }
#pragma unroll
    for (int i = 0; i < 7; ++i) {
        float v = p[i];
#pragma unroll
        for (int o = 32; o > 0; o >>= 1) v += __shfl_xor(v, o);
        p[i] = v;
    }
    if (lane == 0) {
        albuf[wid * 2 + 0] = p[0] + alb[0];
        albuf[wid * 2 + 1] = p[1] + alb[1];
        arbuf[wid * 2 + 0] = p[2] + arb[0];
        arbuf[wid * 2 + 1] = p[3] + arb[1];
        float c0 = p[4] + bc[0], c1 = p[5] + bc[1], c2 = p[6] + bc[2];
        float mx = fmaxf(c0, fmaxf(c1, c2));
        float e0 = __expf(c0 - mx), e1 = __expf(c1 - mx), e2 = __expf(c2 - mx);
        float s = e0 + e1 + e2;
        betab[wid * 3 + 0] = e0 / s;
        betab[wid * 3 + 1] = e1 / s;
        betab[wid * 3 + 2] = e2 / s;
    }
}

// ---------------- K3: per-slice LDS byte-packed histogram ----------------
// grid = 2*NSL blocks; block (m,s) histograms slice s of metapath m.
__global__ __launch_bounds__(256) void k_hist(
    const int* __restrict__ ei1, const int* __restrict__ ei2,
    unsigned* __restrict__ pb, int n, int e)
{
    __shared__ unsigned lds[WMAX];
    const int blk = blockIdx.x;
    const int m = blk / NSL, s = blk % NSL;
    const int* ei = m ? ei2 : ei1;
    const int W = (n + 3) >> 2;

    for (int i = threadIdx.x; i < W; i += 256) lds[i] = 0;
    __syncthreads();

    const int sl = (e + NSL - 1) / NSL;
    const int j0 = s * sl, j1 = min(j0 + sl, e);
    for (int j = j0 + threadIdx.x; j < j1; j += 256) {
        int d = ei[j];
        atomicAdd(&lds[d >> 2], 1u << ((d & 3) * 8));
    }
    __syncthreads();

    unsigned* dst = pb + (size_t)blk * W;
    for (int i = threadIdx.x; i < W; i += 256) dst[i] = lds[i];
}

// ---------------- K4: per-slice exclusive bases (bytes) + totals ----------------
__global__ __launch_bounds__(256) void k_combine(
    unsigned* __restrict__ pb, int* __restrict__ cnt, int n)
{
    const int W = (n + 3) >> 2;
    int t = blockIdx.x * 256 + threadIdx.x;
    if (t >= 2 * W) return;
    const int m = t / W, w = t % W;

    unsigned run = 0;
    unsigned* base = pb + ((size_t)m * NSL) * W + w;
    for (int s = 0; s < NSL; ++s) {
        unsigned v = base[(size_t)s * W];
        base[(size_t)s * W] = run;   // exclusive byte-base of slice s
        run += v;                    // packed adds; each byte <= ~50, no carry
    }
    int bin = 4 * w;
    if (bin + 3 < n) {
        int4 c = make_int4(run & 0xFF, (run >> 8) & 0xFF,
                           (run >> 16) & 0xFF, (run >> 24) & 0xFF);
        *(int4*)&cnt[m * n + bin] = c;
    } else {
        for (int j = 0; j < 4 && bin + j < n; ++j)
            cnt[m * n + bin + j] = (run >> (8 * j)) & 0xFF;
    }
}

// ---------------- K5: exclusive scan over 2N counts (2-level) ----------------
__global__ __launch_bounds__(256) void k_scan1(
    const int* __restrict__ cnt, int* __restrict__ excl,
    int* __restrict__ bsum, int n2)
{
    __shared__ int sh[256];
    int t = threadIdx.x;
    int base = blockIdx.x * 1024 + t * 4;
    int v0 = (base + 0 < n2) ? cnt[base + 0] : 0;
    int v1 = (base + 1 < n2) ? cnt[base + 1] : 0;
    int v2 = (base + 2 < n2) ? cnt[base + 2] : 0;
    int v3 = (base + 3 < n2) ? cnt[base + 3] : 0;
    int s1 = v0 + v1, s2 = s1 + v2, s3 = s2 + v3;
    sh[t] = s3;
    __syncthreads();
    for (int off = 1; off < 256; off <<= 1) {
        int a = (t >= off) ? sh[t - off] : 0;
        __syncthreads();
        sh[t] += a;
        __syncthreads();
    }
    int eb = sh[t] - s3;
    if (t == 255) bsum[blockIdx.x] = sh[255];
    if (base + 0 < n2) excl[base + 0] = eb;
    if (base + 1 < n2) excl[base + 1] = eb + v0;
    if (base + 2 < n2) excl[base + 2] = eb + s1;
    if (base + 3 < n2) excl[base + 3] = eb + s2;
}

__global__ __launch_bounds__(256) void k_scan2(int* __restrict__ bsum, int nb)
{
    __shared__ int sh[256];
    int t = threadIdx.x;
    int v = (t < nb) ? bsum[t] : 0;
    sh[t] = v;
    __syncthreads();
    for (int off = 1; off < 256; off <<= 1) {
        int a = (t >= off) ? sh[t - off] : 0;
        __syncthreads();
        sh[t] += a;
        __syncthreads();
    }
    if (t < nb) bsum[t] = sh[t] - v;
}

__global__ __launch_bounds__(256) void k_scan3(
    int* __restrict__ rp, const int* __restrict__ bsum, int n2, int etot)
{
    int i = blockIdx.x * 256 + threadIdx.x;
    if (i < n2) rp[i] += bsum[i >> 10];
    if (i == 0) rp[n2] = etot;
}

// ---------------- K6: CSR fill via LDS re-rank (no global atomics) ----------------
__global__ __launch_bounds__(256) void k_fill(
    const int* __restrict__ ei1, const int* __restrict__ ei2,
    const unsigned* __restrict__ pb, const int* __restrict__ rp,
    int* __restrict__ srcs, int n, int e)
{
    __shared__ unsigned lds[WMAX];
    const int blk = blockIdx.x;
    const int m = blk / NSL, s = blk % NSL;
    const int* ei = m ? ei2 : ei1;
    const int W = (n + 3) >> 2;

    for (int i = threadIdx.x; i < W; i += 256) lds[i] = 0;
    __syncthreads();

    const unsigned* sb = pb + (size_t)blk * W;
    const int sl = (e + NSL - 1) / NSL;
    const int j0 = s * sl, j1 = min(j0 + sl, e);
    for (int j = j0 + threadIdx.x; j < j1; j += 256) {
        int d  = ei[j];
        int sv = ei[e + j];
        int sh = (d & 3) * 8;
        unsigned old = atomicAdd(&lds[d >> 2], 1u << sh);
        int rank = (old >> sh) & 0xFF;
        int bse  = (sb[d >> 2] >> sh) & 0xFF;
        srcs[rp[m * n + d] + bse + rank] = sv;
    }
}

// ---------------- K7: fused gather (bf16, pipelined) + self + relu ----------------
__global__ __launch_bounds__(256) void k_gather(
    const unsigned* __restrict__ h2,
    const float* __restrict__ albuf, const float* __restrict__ arbuf,
    const float* __restrict__ betab, const float* __restrict__ alpha,
    const int* __restrict__ rp, const int* __restrict__ srcs,
    float* __restrict__ out, int n)
{
    int wid  = blockIdx.x * 4 + (threadIdx.x >> 6);
    if (wid >= n) return;
    int lane = threadIdx.x & 63;

    float b0 = betab[wid * 3 + 0];
    float b1 = betab[wid * 3 + 1];
    float b2 = betab[wid * 3 + 2];

    float2 acc;
    {
        unsigned hu = h2[(size_t)wid * 64 + lane];
        acc.x = b2 * bflo(hu);
        acc.y = b2 * bfhi(hu);
    }

#pragma unroll
    for (int m = 0; m < 2; ++m) {
        const int s0 = rp[m * n + wid];
        const int s1 = rp[m * n + wid + 1];
        const float am  = alpha[m];
        const float arv = arbuf[wid * 2 + m];
        const float bm  = m ? b1 : b0;

        float sum = 0.0f;
        float2 a = {0.0f, 0.0f};

        for (int base = s0; base < s1; base += 64) {
            const int cnt = min(64, s1 - base);

            int   src = 0;
            float ex  = 0.0f;
            if (lane < cnt) {
                src = srcs[base + lane];
                ex  = __expf(am * (albuf[src * 2 + m] + arv));
            }
            {
                float t = ex;
#pragma unroll
                for (int o = 32; o > 0; o >>= 1) t += __shfl_xor(t, o);
                sum += t;
            }

            int j = 0;
            for (; j + 4 <= cnt; j += 4) {
                int   sA = __shfl(src, j + 0), sB = __shfl(src, j + 1);
                int   sC = __shfl(src, j + 2), sD = __shfl(src, j + 3);
                float wA = __shfl(ex,  j + 0), wB = __shfl(ex,  j + 1);
                float wC = __shfl(ex,  j + 2), wD = __shfl(ex,  j + 3);
                unsigned uA = h2[(size_t)sA * 64 + lane];
                unsigned uB = h2[(size_t)sB * 64 + lane];
                unsigned uC = h2[(size_t)sC * 64 + lane];
                unsigned uD = h2[(size_t)sD * 64 + lane];
                a.x = fmaf(wA, bflo(uA), a.x); a.y = fmaf(wA, bfhi(uA), a.y);
                a.x = fmaf(wB, bflo(uB), a.x); a.y = fmaf(wB, bfhi(uB), a.y);
                a.x = fmaf(wC, bflo(uC), a.x); a.y = fmaf(wC, bfhi(uC), a.y);
                a.x = fmaf(wD, bflo(uD), a.x); a.y = fmaf(wD, bfhi(uD), a.y);
            }
            for (; j < cnt; ++j) {
                int   sA = __shfl(src, j);
                float wA = __shfl(ex,  j);
                unsigned uA = h2[(size_t)sA * 64 + lane];
                a.x = fmaf(wA, bflo(uA), a.x);
                a.y = fmaf(wA, bfhi(uA), a.y);
            }
        }

        float sc = bm / (sum + 1e-16f);
        acc.x = fmaf(sc, a.x, acc.x);
        acc.y = fmaf(sc, a.y, acc.y);
    }

    float2 o;
    o.x = fmaxf(acc.x, 0.0f);
    o.y = fmaxf(acc.y, 0.0f);
    *(float2*)(out + (size_t)wid * DIM + lane * 2) = o;
}

extern "C" void kernel_launch(void* const* d_in, const int* in_sizes, int n_in,
                              void* d_out, int out_size, void* d_ws, size_t ws_size,
                              hipStream_t stream)
{
    const float* x     = (const float*)d_in[0];
    const int*   ei1   = (const int*)d_in[1];
    const int*   ei2   = (const int*)d_in[2];
    const float* W_lin = (const float*)d_in[3];
    const float* b_lin = (const float*)d_in[4];
    const float* W_cv  = (const float*)d_in[5];
    const float* b_cv  = (const float*)d_in[6];
    const float* alw   = (const float*)d_in[7];
    const float* alb   = (const float*)d_in[8];
    const float* arw   = (const float*)d_in[9];
    const float* arb   = (const float*)d_in[10];
    const float* alpha = (const float*)d_in[11];

    const int N  = in_sizes[0] / DIM;
    const int E  = in_sizes[1] / 2;
    const int N2 = 2 * N;
    const int W  = (N + 3) >> 2;

    float* out = (float*)d_out;

    // workspace layout (4-byte units)
    unsigned* h2    = (unsigned*)d_ws;                  // N*64
    float*    albuf = (float*)(h2 + (size_t)N * 64);    // 2N
    float*    arbuf = albuf + (size_t)2 * N;            // 2N
    float*    betab = arbuf + (size_t)2 * N;            // 3N
    int*      rp    = (int*)(betab + (size_t)3 * N);    // 2N+2
    int*      cnt   = rp + (N2 + 2);                    // 2N
    int*      bsum  = cnt + N2;                         // 256
    unsigned* pb    = (unsigned*)(bsum + 256);          // 2*NSL*W
    int*      srcs  = (int*)(pb + (size_t)2 * NSL * W); // 2E

    const int nb = (N2 + 1023) / 1024;

    k_gemm_h<<<(N + 63) / 64, 256, 0, stream>>>(x, W_lin, b_lin,
                                                (unsigned short*)h2, N);

    k_hist<<<2 * NSL, 256, 0, stream>>>(ei1, ei2, pb, N, E);

    k_node_vec<<<(N + 3) / 4, 256, 0, stream>>>(x, h2, W_cv, b_cv, alw, alb,
                                                arw, arb, albuf, arbuf, betab, N);

    k_combine<<<(2 * W + 255) / 256, 256, 0, stream>>>(pb, cnt, N);

    k_scan1<<<nb, 256, 0, stream>>>(cnt, rp, bsum, N2);
    k_scan2<<<1, 256, 0, stream>>>(bsum, nb);
    k_scan3<<<(N2 + 255) / 256, 256, 0, stream>>>(rp, bsum, N2, 2 * E);

    k_fill<<<2 * NSL, 256, 0, stream>>>(ei1, ei2, pb, rp, srcs, N, E);

    k_gather<<<(N + 3) / 4, 256, 0, stream>>>(h2, albuf, arbuf, betab, alpha,
                                              rp, srcs, out, N);
}

// Round 7
// 331.798 us; speedup vs baseline: 8.9768x; 1.0282x over previous
//
#include <hip/hip_runtime.h>

#define DIM 128
#define NSL 128            // edge slices per metapath
#define HSEG 50000         // nodes per histogram segment
#define WSEG 12500         // HSEG/4 packed-byte words (50 KB LDS)

typedef __attribute__((ext_vector_type(8))) short bf16x8;
typedef __attribute__((ext_vector_type(4))) float f32x4;

__device__ __forceinline__ unsigned bfbits(float f) {
    unsigned u = __float_as_uint(f);
    return (u + 0x7FFFu + ((u >> 16) & 1u)) >> 16;   // RNE bf16
}
__device__ __forceinline__ float bflo(unsigned u) { return __uint_as_float(u << 16); }
__device__ __forceinline__ float bfhi(unsigned u) { return __uint_as_float(u & 0xFFFF0000u); }

// ---------------- K1: h2(bf16) = x @ W_lin^T + b_lin via MFMA ----------------
__global__ __launch_bounds__(256) void k_gemm_h(
    const float* __restrict__ x, const float* __restrict__ W,
    const float* __restrict__ b, unsigned short* __restrict__ h2u, int n)
{
    __shared__ short wlds[128 * 136];
    __shared__ short xlds[64 * 136];
    const int tid  = threadIdx.x;
    const int row0 = blockIdx.x * 64;

    {
        const int j = tid >> 1, half = tid & 1;
        const float4* W4 = (const float4*)W;
#pragma unroll
        for (int i = 0; i < 8; ++i) {
            float4 fa = W4[j * 32 + half * 16 + i * 2];
            float4 fb = W4[j * 32 + half * 16 + i * 2 + 1];
            uint4 p;
            p.x = bfbits(fa.x) | (bfbits(fa.y) << 16);
            p.y = bfbits(fa.z) | (bfbits(fa.w) << 16);
            p.z = bfbits(fb.x) | (bfbits(fb.y) << 16);
            p.w = bfbits(fb.z) | (bfbits(fb.w) << 16);
            *(uint4*)&wlds[j * 136 + half * 64 + i * 8] = p;
        }
    }
    {
        const int r = tid >> 2, q = tid & 3;
        const int row = min(row0 + r, n - 1);
        const float4* x4 = (const float4*)x;
#pragma unroll
        for (int i = 0; i < 4; ++i) {
            float4 fa = x4[(size_t)row * 32 + q * 8 + i * 2];
            float4 fb = x4[(size_t)row * 32 + q * 8 + i * 2 + 1];
            uint4 p;
            p.x = bfbits(fa.x) | (bfbits(fa.y) << 16);
            p.y = bfbits(fa.z) | (bfbits(fa.w) << 16);
            p.z = bfbits(fb.x) | (bfbits(fb.y) << 16);
            p.w = bfbits(fb.z) | (bfbits(fb.w) << 16);
            *(uint4*)&xlds[r * 136 + q * 32 + i * 8] = p;
        }
    }
    __syncthreads();

    const int wv = tid >> 6, lane = tid & 63;
    const int lr = lane & 15, lg = lane >> 4;

    f32x4 acc[8];
#pragma unroll
    for (int c = 0; c < 8; ++c) acc[c] = (f32x4){0.f, 0.f, 0.f, 0.f};

#pragma unroll
    for (int ks = 0; ks < 4; ++ks) {
        bf16x8 a = *(const bf16x8*)&xlds[(wv * 16 + lr) * 136 + ks * 32 + lg * 8];
#pragma unroll
        for (int c = 0; c < 8; ++c) {
            bf16x8 bb = *(const bf16x8*)&wlds[(c * 16 + lr) * 136 + ks * 32 + lg * 8];
            acc[c] = __builtin_amdgcn_mfma_f32_16x16x32_bf16(a, bb, acc[c], 0, 0, 0);
        }
    }

    const int rbase = row0 + wv * 16 + lg * 4;
#pragma unroll
    for (int c = 0; c < 8; ++c) {
        const int col = c * 16 + lr;
        const float bc = b[col];
#pragma unroll
        for (int r = 0; r < 4; ++r) {
            const int row = rbase + r;
            if (row < n)
                h2u[(size_t)row * DIM + col] = (unsigned short)bfbits(acc[c][r] + bc);
        }
    }
}

// ---------------- K2: per-node al, ar, beta (h from bf16 h2) ----------------
__global__ __launch_bounds__(256) void k_node_vec(
    const float* __restrict__ x, const unsigned* __restrict__ h2,
    const float* __restrict__ Wc, const float* __restrict__ bc,
    const float* __restrict__ alw, const float* __restrict__ alb,
    const float* __restrict__ arw, const float* __restrict__ arb,
    float* __restrict__ albuf, float* __restrict__ arbuf,
    float* __restrict__ betab, int n)
{
    int wid  = blockIdx.x * 4 + (threadIdx.x >> 6);
    int lane = threadIdx.x & 63;
    if (wid >= n) return;

    const float2 x2 = *(const float2*)(x + (size_t)wid * DIM + lane * 2);
    const unsigned hu = h2[(size_t)wid * 64 + lane];
    const float hx = bflo(hu), hy = bfhi(hu);

    float p[7];
    {
        float2 w;
        w = *(const float2*)(alw + 0 * DIM + lane * 2); p[0] = hx * w.x + hy * w.y;
        w = *(const float2*)(alw + 1 * DIM + lane * 2); p[1] = hx * w.x + hy * w.y;
        w = *(const float2*)(arw + 0 * DIM + lane * 2); p[2] = hx * w.x + hy * w.y;
        w = *(const float2*)(arw + 1 * DIM + lane * 2); p[3] = hx * w.x + hy * w.y;
        w = *(const float2*)(Wc  + 0 * DIM + lane * 2); p[4] = x2.x * w.x + x2.y * w.y;
        w = *(const float2*)(Wc  + 1 * DIM + lane * 2); p[5] = x2.x * w.x + x2.y * w.y;
        w = *(const float2*)(Wc  + 2 * DIM + lane * 2); p[6] = x2.x * w.x + x2.y * w.y;
    }
#pragma unroll
    for (int i = 0; i < 7; ++i) {
        float v = p[i];
#pragma unroll
        for (int o = 32; o > 0; o >>= 1) v += __shfl_xor(v, o);
        p[i] = v;
    }
    if (lane == 0) {
        albuf[wid * 2 + 0] = p[0] + alb[0];
        albuf[wid * 2 + 1] = p[1] + alb[1];
        arbuf[wid * 2 + 0] = p[2] + arb[0];
        arbuf[wid * 2 + 1] = p[3] + arb[1];
        float c0 = p[4] + bc[0], c1 = p[5] + bc[1], c2 = p[6] + bc[2];
        float mx = fmaxf(c0, fmaxf(c1, c2));
        float e0 = __expf(c0 - mx), e1 = __expf(c1 - mx), e2 = __expf(c2 - mx);
        float s = e0 + e1 + e2;
        betab[wid * 3 + 0] = e0 / s;
        betab[wid * 3 + 1] = e1 / s;
        betab[wid * 3 + 2] = e2 / s;
    }
}

// ---------------- K3: per-(metapath,segment,slice) LDS histogram ----------------
// blk = ((m*NSEG)+seg)*NSL + s ; 50 KB LDS -> 3 blocks/CU
__global__ __launch_bounds__(256) void k_hist(
    const int* __restrict__ ei1, const int* __restrict__ ei2,
    unsigned* __restrict__ pb, int nseg, int n, int e)
{
    __shared__ unsigned lds[WSEG];
    const int blk = blockIdx.x;
    const int s   = blk % NSL;
    const int seg = (blk / NSL) % nseg;
    const int m   = blk / (NSL * nseg);
    const int* ei = m ? ei2 : ei1;
    const int d0  = seg * HSEG;
    const int W   = (min(n - d0, HSEG) + 3) >> 2;

    for (int i = threadIdx.x; i < W; i += 256) lds[i] = 0;
    __syncthreads();

    const int sl = (e + NSL - 1) / NSL;
    const int j0 = s * sl, j1 = min(j0 + sl, e);
    for (int j = j0 + threadIdx.x; j < j1; j += 256) {
        int dl = ei[j] - d0;
        if ((unsigned)dl < (unsigned)HSEG)
            atomicAdd(&lds[dl >> 2], 1u << ((dl & 3) * 8));
    }
    __syncthreads();

    unsigned* dst = pb + (size_t)blk * WSEG;
    for (int i = threadIdx.x; i < W; i += 256) dst[i] = lds[i];
}

// ---------------- K4: per-slice exclusive byte-bases + totals ----------------
__global__ __launch_bounds__(256) void k_combine(
    unsigned* __restrict__ pb, int* __restrict__ cnt, int nseg, int n)
{
    int t = blockIdx.x * 256 + threadIdx.x;
    if (t >= 2 * nseg * WSEG) return;
    const int w   = t % WSEG;
    const int seg = (t / WSEG) % nseg;
    const int m   = t / (WSEG * nseg);
    const int d0  = seg * HSEG;

    unsigned run = 0;
    unsigned* base = pb + ((size_t)(m * nseg + seg) * NSL) * WSEG + w;
    for (int s = 0; s < NSL; ++s) {
        unsigned v = base[(size_t)s * WSEG];
        base[(size_t)s * WSEG] = run;   // exclusive byte-base of slice s
        run += v;                       // packed adds; bytes <= ~50, no carry
    }
    int bin = d0 + 4 * w;
    if (bin + 3 < n && 4 * w + 3 < HSEG) {
        int4 c = make_int4(run & 0xFF, (run >> 8) & 0xFF,
                           (run >> 16) & 0xFF, (run >> 24) & 0xFF);
        *(int4*)&cnt[m * n + bin] = c;
    } else {
        for (int j = 0; j < 4 && bin + j < n && 4 * w + j < HSEG; ++j)
            cnt[m * n + bin + j] = (run >> (8 * j)) & 0xFF;
    }
}

// ---------------- K5: exclusive scan over 2N counts (2-level) ----------------
__global__ __launch_bounds__(256) void k_scan1(
    const int* __restrict__ cnt, int* __restrict__ excl,
    int* __restrict__ bsum, int n2)
{
    __shared__ int sh[256];
    int t = threadIdx.x;
    int base = blockIdx.x * 1024 + t * 4;
    int v0 = (base + 0 < n2) ? cnt[base + 0] : 0;
    int v1 = (base + 1 < n2) ? cnt[base + 1] : 0;
    int v2 = (base + 2 < n2) ? cnt[base + 2] : 0;
    int v3 = (base + 3 < n2) ? cnt[base + 3] : 0;
    int s1 = v0 + v1, s2 = s1 + v2, s3 = s2 + v3;
    sh[t] = s3;
    __syncthreads();
    for (int off = 1; off < 256; off <<= 1) {
        int a = (t >= off) ? sh[t - off] : 0;
        __syncthreads();
        sh[t] += a;
        __syncthreads();
    }
    int eb = sh[t] - s3;
    if (t == 255) bsum[blockIdx.x] = sh[255];
    if (base + 0 < n2) excl[base + 0] = eb;
    if (base + 1 < n2) excl[base + 1] = eb + v0;
    if (base + 2 < n2) excl[base + 2] = eb + s1;
    if (base + 3 < n2) excl[base + 3] = eb + s2;
}

__global__ __launch_bounds__(256) void k_scan2(int* __restrict__ bsum, int nb)
{
    __shared__ int sh[256];
    int t = threadIdx.x;
    int v = (t < nb) ? bsum[t] : 0;
    sh[t] = v;
    __syncthreads();
    for (int off = 1; off < 256; off <<= 1) {
        int a = (t >= off) ? sh[t - off] : 0;
        __syncthreads();
        sh[t] += a;
        __syncthreads();
    }
    if (t < nb) bsum[t] = sh[t] - v;
}

__global__ __launch_bounds__(256) void k_scan3(
    int* __restrict__ rp, const int* __restrict__ bsum, int n2, int etot)
{
    int i = blockIdx.x * 256 + threadIdx.x;
    if (i < n2) rp[i] += bsum[i >> 10];
    if (i == 0) rp[n2] = etot;
}

// ---------------- K6: CSR fill via LDS re-rank (no global atomics) ----------------
__global__ __launch_bounds__(256) void k_fill(
    const int* __restrict__ ei1, const int* __restrict__ ei2,
    const unsigned* __restrict__ pb, const int* __restrict__ rp,
    int* __restrict__ srcs, int nseg, int n, int e)
{
    __shared__ unsigned lds[WSEG];
    const int blk = blockIdx.x;
    const int s   = blk % NSL;
    const int seg = (blk / NSL) % nseg;
    const int m   = blk / (NSL * nseg);
    const int* ei = m ? ei2 : ei1;
    const int d0  = seg * HSEG;
    const int W   = (min(n - d0, HSEG) + 3) >> 2;

    for (int i = threadIdx.x; i < W; i += 256) lds[i] = 0;
    __syncthreads();

    const unsigned* sb = pb + (size_t)blk * WSEG;
    const int sl = (e + NSL - 1) / NSL;
    const int j0 = s * sl, j1 = min(j0 + sl, e);
    for (int j = j0 + threadIdx.x; j < j1; j += 256) {
        int d  = ei[j];
        int dl = d - d0;
        if ((unsigned)dl < (unsigned)HSEG) {
            int sv = ei[e + j];
            int sh = (dl & 3) * 8;
            unsigned old = atomicAdd(&lds[dl >> 2], 1u << sh);
            int rank = (old >> sh) & 0xFF;
            int bse  = (sb[dl >> 2] >> sh) & 0xFF;
            srcs[rp[m * n + d] + bse + rank] = sv;
        }
    }
}

// ---------------- K7: fused gather (bf16, scalar-broadcast) + self + relu ------
__global__ __launch_bounds__(256) void k_gather(
    const unsigned* __restrict__ h2,
    const float* __restrict__ albuf, const float* __restrict__ arbuf,
    const float* __restrict__ betab, const float* __restrict__ alpha,
    const int* __restrict__ rp, const int* __restrict__ srcs,
    float* __restrict__ out, int n)
{
    int wid  = blockIdx.x * 4 + (threadIdx.x >> 6);
    if (wid >= n) return;
    int lane = threadIdx.x & 63;

    float b0 = betab[wid * 3 + 0];
    float b1 = betab[wid * 3 + 1];
    float b2 = betab[wid * 3 + 2];

    float2 acc;
    {
        unsigned hu = h2[(size_t)wid * 64 + lane];
        acc.x = b2 * bflo(hu);
        acc.y = b2 * bfhi(hu);
    }

#pragma unroll
    for (int m = 0; m < 2; ++m) {
        const int s0 = rp[m * n + wid];
        const int s1 = rp[m * n + wid + 1];
        const float am  = alpha[m];
        const float arv = arbuf[wid * 2 + m];
        const float bm  = m ? b1 : b0;

        float sum = 0.0f;
        float2 a = {0.0f, 0.0f};

        for (int base = s0; base < s1; base += 64) {
            const int cnt = min(64, s1 - base);

            int   src = 0;
            float ex  = 0.0f;
            if (lane < cnt) {
                src = srcs[base + lane];
                ex  = __expf(am * (albuf[src * 2 + m] + arv));
            }
            {
                float t = ex;
#pragma unroll
                for (int o = 32; o > 0; o >>= 1) t += __shfl_xor(t, o);
                sum += t;
            }

            const unsigned exu = __float_as_uint(ex);
            int j = 0;
            for (; j + 4 <= cnt; j += 4) {
                // wave-uniform j -> readlane puts src/weight into SGPRs:
                // scalar row base + per-lane constant offset, SGPR-operand fmac
                int   sA = __builtin_amdgcn_readlane(src, j + 0);
                int   sB = __builtin_amdgcn_readlane(src, j + 1);
                int   sC = __builtin_amdgcn_readlane(src, j + 2);
                int   sD = __builtin_amdgcn_readlane(src, j + 3);
                float wA = __uint_as_float(__builtin_amdgcn_readlane(exu, j + 0));
                float wB = __uint_as_float(__builtin_amdgcn_readlane(exu, j + 1));
                float wC = __uint_as_float(__builtin_amdgcn_readlane(exu, j + 2));
                float wD = __uint_as_float(__builtin_amdgcn_readlane(exu, j + 3));
                unsigned uA = h2[(size_t)sA * 64 + lane];
                unsigned uB = h2[(size_t)sB * 64 + lane];
                unsigned uC = h2[(size_t)sC * 64 + lane];
                unsigned uD = h2[(size_t)sD * 64 + lane];
                a.x = fmaf(wA, bflo(uA), a.x); a.y = fmaf(wA, bfhi(uA), a.y);
                a.x = fmaf(wB, bflo(uB), a.x); a.y = fmaf(wB, bfhi(uB), a.y);
                a.x = fmaf(wC, bflo(uC), a.x); a.y = fmaf(wC, bfhi(uC), a.y);
                a.x = fmaf(wD, bflo(uD), a.x); a.y = fmaf(wD, bfhi(uD), a.y);
            }
            for (; j < cnt; ++j) {
                int   sA = __builtin_amdgcn_readlane(src, j);
                float wA = __uint_as_float(__builtin_amdgcn_readlane(exu, j));
                unsigned uA = h2[(size_t)sA * 64 + lane];
                a.x = fmaf(wA, bflo(uA), a.x);
                a.y = fmaf(wA, bfhi(uA), a.y);
            }
        }

        float sc = bm / (sum + 1e-16f);
        acc.x = fmaf(sc, a.x, acc.x);
        acc.y = fmaf(sc, a.y, acc.y);
    }

    float2 o;
    o.x = fmaxf(acc.x, 0.0f);
    o.y = fmaxf(acc.y, 0.0f);
    *(float2*)(out + (size_t)wid * DIM + lane * 2) = o;
}

extern "C" void kernel_launch(void* const* d_in, const int* in_sizes, int n_in,
                              void* d_out, int out_size, void* d_ws, size_t ws_size,
                              hipStream_t stream)
{
    const float* x     = (const float*)d_in[0];
    const int*   ei1   = (const int*)d_in[1];
    const int*   ei2   = (const int*)d_in[2];
    const float* W_lin = (const float*)d_in[3];
    const float* b_lin = (const float*)d_in[4];
    const float* W_cv  = (const float*)d_in[5];
    const float* b_cv  = (const float*)d_in[6];
    const float* alw   = (const float*)d_in[7];
    const float* alb   = (const float*)d_in[8];
    const float* arw   = (const float*)d_in[9];
    const float* arb   = (const float*)d_in[10];
    const float* alpha = (const float*)d_in[11];

    const int N    = in_sizes[0] / DIM;
    const int E    = in_sizes[1] / 2;
    const int N2   = 2 * N;
    const int NSEG = (N + HSEG - 1) / HSEG;

    float* out = (float*)d_out;

    // workspace layout (4-byte units)
    unsigned* h2    = (unsigned*)d_ws;                  // N*64
    float*    albuf = (float*)(h2 + (size_t)N * 64);    // 2N
    float*    arbuf = albuf + (size_t)2 * N;            // 2N
    float*    betab = arbuf + (size_t)2 * N;            // 3N
    int*      rp    = (int*)(betab + (size_t)3 * N);    // 2N+2
    int*      cnt   = rp + (N2 + 2);                    // 2N
    int*      bsum  = cnt + N2;                         // 256
    unsigned* pb    = (unsigned*)(bsum + 256);          // 2*NSEG*NSL*WSEG
    int*      srcs  = (int*)(pb + (size_t)2 * NSEG * NSL * WSEG); // 2E

    const int nb     = (N2 + 1023) / 1024;
    const int nhblk  = 2 * NSEG * NSL;

    k_gemm_h<<<(N + 63) / 64, 256, 0, stream>>>(x, W_lin, b_lin,
                                                (unsigned short*)h2, N);

    k_hist<<<nhblk, 256, 0, stream>>>(ei1, ei2, pb, NSEG, N, E);

    k_node_vec<<<(N + 3) / 4, 256, 0, stream>>>(x, h2, W_cv, b_cv, alw, alb,
                                                arw, arb, albuf, arbuf, betab, N);

    k_combine<<<(2 * NSEG * WSEG + 255) / 256, 256, 0, stream>>>(pb, cnt, NSEG, N);

    k_scan1<<<nb, 256, 0, stream>>>(cnt, rp, bsum, N2);
    k_scan2<<<1, 256, 0, stream>>>(bsum, nb);
    k_scan3<<<(N2 + 255) / 256, 256, 0, stream>>>(rp, bsum, N2, 2 * E);

    k_fill<<<nhblk, 256, 0, stream>>>(ei1, ei2, pb, rp, srcs, NSEG, N, E);

    k_gather<<<(N + 3) / 4, 256, 0, stream>>>(h2, albuf, arbuf, betab, alpha,
                                              rp, srcs, out, N);
}

// Round 8
// 329.309 us; speedup vs baseline: 9.0447x; 1.0076x over previous
//
#include <hip/hip_runtime.h>

#define DIM 128
#define NSL 128            // edge slices per metapath
#define HSEG 50000         // nodes per histogram segment
#define WSEG 12500         // HSEG/4 packed-byte words (50 KB LDS)

typedef __attribute__((ext_vector_type(8))) short bf16x8;
typedef __attribute__((ext_vector_type(4))) float f32x4;

__device__ __forceinline__ unsigned bfbits(float f) {
    unsigned u = __float_as_uint(f);
    return (u + 0x7FFFu + ((u >> 16) & 1u)) >> 16;   // RNE bf16
}
__device__ __forceinline__ float bflo(unsigned u) { return __uint_as_float(u << 16); }
__device__ __forceinline__ float bfhi(unsigned u) { return __uint_as_float(u & 0xFFFF0000u); }

// ---------------- K1: h2(bf16) = x @ W_lin^T + b_lin via MFMA ----------------
__global__ __launch_bounds__(256) void k_gemm_h(
    const float* __restrict__ x, const float* __restrict__ W,
    const float* __restrict__ b, unsigned short* __restrict__ h2u, int n)
{
    __shared__ short wlds[128 * 136];
    __shared__ short xlds[64 * 136];
    const int tid  = threadIdx.x;
    const int row0 = blockIdx.x * 64;

    {
        const int j = tid >> 1, half = tid & 1;
        const float4* W4 = (const float4*)W;
#pragma unroll
        for (int i = 0; i < 8; ++i) {
            float4 fa = W4[j * 32 + half * 16 + i * 2];
            float4 fb = W4[j * 32 + half * 16 + i * 2 + 1];
            uint4 p;
            p.x = bfbits(fa.x) | (bfbits(fa.y) << 16);
            p.y = bfbits(fa.z) | (bfbits(fa.w) << 16);
            p.z = bfbits(fb.x) | (bfbits(fb.y) << 16);
            p.w = bfbits(fb.z) | (bfbits(fb.w) << 16);
            *(uint4*)&wlds[j * 136 + half * 64 + i * 8] = p;
        }
    }
    {
        const int r = tid >> 2, q = tid & 3;
        const int row = min(row0 + r, n - 1);
        const float4* x4 = (const float4*)x;
#pragma unroll
        for (int i = 0; i < 4; ++i) {
            float4 fa = x4[(size_t)row * 32 + q * 8 + i * 2];
            float4 fb = x4[(size_t)row * 32 + q * 8 + i * 2 + 1];
            uint4 p;
            p.x = bfbits(fa.x) | (bfbits(fa.y) << 16);
            p.y = bfbits(fa.z) | (bfbits(fa.w) << 16);
            p.z = bfbits(fb.x) | (bfbits(fb.y) << 16);
            p.w = bfbits(fb.z) | (bfbits(fb.w) << 16);
            *(uint4*)&xlds[r * 136 + q * 32 + i * 8] = p;
        }
    }
    __syncthreads();

    const int wv = tid >> 6, lane = tid & 63;
    const int lr = lane & 15, lg = lane >> 4;

    f32x4 acc[8];
#pragma unroll
    for (int c = 0; c < 8; ++c) acc[c] = (f32x4){0.f, 0.f, 0.f, 0.f};

#pragma unroll
    for (int ks = 0; ks < 4; ++ks) {
        bf16x8 a = *(const bf16x8*)&xlds[(wv * 16 + lr) * 136 + ks * 32 + lg * 8];
#pragma unroll
        for (int c = 0; c < 8; ++c) {
            bf16x8 bb = *(const bf16x8*)&wlds[(c * 16 + lr) * 136 + ks * 32 + lg * 8];
            acc[c] = __builtin_amdgcn_mfma_f32_16x16x32_bf16(a, bb, acc[c], 0, 0, 0);
        }
    }

    const int rbase = row0 + wv * 16 + lg * 4;
#pragma unroll
    for (int c = 0; c < 8; ++c) {
        const int col = c * 16 + lr;
        const float bc = b[col];
#pragma unroll
        for (int r = 0; r < 4; ++r) {
            const int row = rbase + r;
            if (row < n)
                h2u[(size_t)row * DIM + col] = (unsigned short)bfbits(acc[c][r] + bc);
        }
    }
}

// ---------------- K2: per-node al, ar, beta (h from bf16 h2) ----------------
__global__ __launch_bounds__(256) void k_node_vec(
    const float* __restrict__ x, const unsigned* __restrict__ h2,
    const float* __restrict__ Wc, const float* __restrict__ bc,
    const float* __restrict__ alw, const float* __restrict__ alb,
    const float* __restrict__ arw, const float* __restrict__ arb,
    float* __restrict__ albuf, float* __restrict__ arbuf,
    float* __restrict__ betab, int n)
{
    int wid  = blockIdx.x * 4 + (threadIdx.x >> 6);
    int lane = threadIdx.x & 63;
    if (wid >= n) return;

    const float2 x2 = *(const float2*)(x + (size_t)wid * DIM + lane * 2);
    const unsigned hu = h2[(size_t)wid * 64 + lane];
    const float hx = bflo(hu), hy = bfhi(hu);

    float p[7];
    {
        float2 w;
        w = *(const float2*)(alw + 0 * DIM + lane * 2); p[0] = hx * w.x + hy * w.y;
        w = *(const float2*)(alw + 1 * DIM + lane * 2); p[1] = hx * w.x + hy * w.y;
        w = *(const float2*)(arw + 0 * DIM + lane * 2); p[2] = hx * w.x + hy * w.y;
        w = *(const float2*)(arw + 1 * DIM + lane * 2); p[3] = hx * w.x + hy * w.y;
        w = *(const float2*)(Wc  + 0 * DIM + lane * 2); p[4] = x2.x * w.x + x2.y * w.y;
        w = *(const float2*)(Wc  + 1 * DIM + lane * 2); p[5] = x2.x * w.x + x2.y * w.y;
        w = *(const float2*)(Wc  + 2 * DIM + lane * 2); p[6] = x2.x * w.x + x2.y * w.y;
    }
#pragma unroll
    for (int i = 0; i < 7; ++i) {
        float v = p[i];
#pragma unroll
        for (int o = 32; o > 0; o >>= 1) v += __shfl_xor(v, o);
        p[i] = v;
    }
    if (lane == 0) {
        albuf[wid * 2 + 0] = p[0] + alb[0];
        albuf[wid * 2 + 1] = p[1] + alb[1];
        arbuf[wid * 2 + 0] = p[2] + arb[0];
        arbuf[wid * 2 + 1] = p[3] + arb[1];
        float c0 = p[4] + bc[0], c1 = p[5] + bc[1], c2 = p[6] + bc[2];
        float mx = fmaxf(c0, fmaxf(c1, c2));
        float e0 = __expf(c0 - mx), e1 = __expf(c1 - mx), e2 = __expf(c2 - mx);
        float s = e0 + e1 + e2;
        betab[wid * 3 + 0] = e0 / s;
        betab[wid * 3 + 1] = e1 / s;
        betab[wid * 3 + 2] = e2 / s;
    }
}

// ---------------- K3: per-(metapath,segment,slice) LDS histogram ----------------
__global__ __launch_bounds__(256) void k_hist(
    const int* __restrict__ ei1, const int* __restrict__ ei2,
    unsigned* __restrict__ pb, int nseg, int n, int e)
{
    __shared__ unsigned lds[WSEG];
    const int blk = blockIdx.x;
    const int s   = blk % NSL;
    const int seg = (blk / NSL) % nseg;
    const int m   = blk / (NSL * nseg);
    const int* ei = m ? ei2 : ei1;
    const int d0  = seg * HSEG;
    const int W   = (min(n - d0, HSEG) + 3) >> 2;

    for (int i = threadIdx.x; i < W; i += 256) lds[i] = 0;
    __syncthreads();

    const int sl = (e + NSL - 1) / NSL;
    const int j0 = s * sl, j1 = min(j0 + sl, e);
    for (int j = j0 + threadIdx.x; j < j1; j += 256) {
        int dl = ei[j] - d0;
        if ((unsigned)dl < (unsigned)HSEG)
            atomicAdd(&lds[dl >> 2], 1u << ((dl & 3) * 8));
    }
    __syncthreads();

    unsigned* dst = pb + (size_t)blk * WSEG;
    for (int i = threadIdx.x; i < W; i += 256) dst[i] = lds[i];
}

// ---------------- K4: per-slice exclusive byte-bases + totals ----------------
__global__ __launch_bounds__(256) void k_combine(
    unsigned* __restrict__ pb, int* __restrict__ cnt, int nseg, int n)
{
    int t = blockIdx.x * 256 + threadIdx.x;
    if (t >= 2 * nseg * WSEG) return;
    const int w   = t % WSEG;
    const int seg = (t / WSEG) % nseg;
    const int m   = t / (WSEG * nseg);
    const int d0  = seg * HSEG;

    unsigned run = 0;
    unsigned* base = pb + ((size_t)(m * nseg + seg) * NSL) * WSEG + w;
    for (int s = 0; s < NSL; ++s) {
        unsigned v = base[(size_t)s * WSEG];
        base[(size_t)s * WSEG] = run;   // exclusive byte-base of slice s
        run += v;                       // packed adds; bytes <= ~50, no carry
    }
    int bin = d0 + 4 * w;
    if (bin + 3 < n && 4 * w + 3 < HSEG) {
        int4 c = make_int4(run & 0xFF, (run >> 8) & 0xFF,
                           (run >> 16) & 0xFF, (run >> 24) & 0xFF);
        *(int4*)&cnt[m * n + bin] = c;
    } else {
        for (int j = 0; j < 4 && bin + j < n && 4 * w + j < HSEG; ++j)
            cnt[m * n + bin + j] = (run >> (8 * j)) & 0xFF;
    }
}

// ---------------- K5: exclusive scan over 2N counts (2-level) ----------------
__global__ __launch_bounds__(256) void k_scan1(
    const int* __restrict__ cnt, int* __restrict__ excl,
    int* __restrict__ bsum, int n2)
{
    __shared__ int sh[256];
    int t = threadIdx.x;
    int base = blockIdx.x * 1024 + t * 4;
    int v0 = (base + 0 < n2) ? cnt[base + 0] : 0;
    int v1 = (base + 1 < n2) ? cnt[base + 1] : 0;
    int v2 = (base + 2 < n2) ? cnt[base + 2] : 0;
    int v3 = (base + 3 < n2) ? cnt[base + 3] : 0;
    int s1 = v0 + v1, s2 = s1 + v2, s3 = s2 + v3;
    sh[t] = s3;
    __syncthreads();
    for (int off = 1; off < 256; off <<= 1) {
        int a = (t >= off) ? sh[t - off] : 0;
        __syncthreads();
        sh[t] += a;
        __syncthreads();
    }
    int eb = sh[t] - s3;
    if (t == 255) bsum[blockIdx.x] = sh[255];
    if (base + 0 < n2) excl[base + 0] = eb;
    if (base + 1 < n2) excl[base + 1] = eb + v0;
    if (base + 2 < n2) excl[base + 2] = eb + s1;
    if (base + 3 < n2) excl[base + 3] = eb + s2;
}

__global__ __launch_bounds__(256) void k_scan2(int* __restrict__ bsum, int nb)
{
    __shared__ int sh[256];
    int t = threadIdx.x;
    int v = (t < nb) ? bsum[t] : 0;
    sh[t] = v;
    __syncthreads();
    for (int off = 1; off < 256; off <<= 1) {
        int a = (t >= off) ? sh[t - off] : 0;
        __syncthreads();
        sh[t] += a;
        __syncthreads();
    }
    if (t < nb) bsum[t] = sh[t] - v;
}

__global__ __launch_bounds__(256) void k_scan3(
    int* __restrict__ rp, const int* __restrict__ bsum, int n2, int etot)
{
    int i = blockIdx.x * 256 + threadIdx.x;
    if (i < n2) rp[i] += bsum[i >> 10];
    if (i == 0) rp[n2] = etot;
}

// ---------------- K6: CSR fill via LDS re-rank (no global atomics) ----------------
__global__ __launch_bounds__(256) void k_fill(
    const int* __restrict__ ei1, const int* __restrict__ ei2,
    const unsigned* __restrict__ pb, const int* __restrict__ rp,
    int* __restrict__ srcs, int nseg, int n, int e)
{
    __shared__ unsigned lds[WSEG];
    const int blk = blockIdx.x;
    const int s   = blk % NSL;
    const int seg = (blk / NSL) % nseg;
    const int m   = blk / (NSL * nseg);
    const int* ei = m ? ei2 : ei1;
    const int d0  = seg * HSEG;
    const int W   = (min(n - d0, HSEG) + 3) >> 2;

    for (int i = threadIdx.x; i < W; i += 256) lds[i] = 0;
    __syncthreads();

    const unsigned* sb = pb + (size_t)blk * WSEG;
    const int sl = (e + NSL - 1) / NSL;
    const int j0 = s * sl, j1 = min(j0 + sl, e);
    for (int j = j0 + threadIdx.x; j < j1; j += 256) {
        int d  = ei[j];
        int dl = d - d0;
        if ((unsigned)dl < (unsigned)HSEG) {
            int sv = ei[e + j];
            int sh = (dl & 3) * 8;
            unsigned old = atomicAdd(&lds[dl >> 2], 1u << sh);
            int rank = (old >> sh) & 0xFF;
            int bse  = (sb[dl >> 2] >> sh) & 0xFF;
            srcs[rp[m * n + d] + bse + rank] = sv;
        }
    }
}

// ---------------- K7: fused gather (bf16, 8-deep pipelined) + self + relu ------
__global__ __launch_bounds__(256) void k_gather(
    const unsigned* __restrict__ h2,
    const float* __restrict__ albuf, const float* __restrict__ arbuf,
    const float* __restrict__ betab, const float* __restrict__ alpha,
    const int* __restrict__ rp, const int* __restrict__ srcs,
    float* __restrict__ out, int n)
{
    int wid  = blockIdx.x * 4 + (threadIdx.x >> 6);
    if (wid >= n) return;
    int lane = threadIdx.x & 63;

    float b0 = betab[wid * 3 + 0];
    float b1 = betab[wid * 3 + 1];
    float b2 = betab[wid * 3 + 2];

    float2 acc;
    {
        unsigned hu = h2[(size_t)wid * 64 + lane];
        acc.x = b2 * bflo(hu);
        acc.y = b2 * bfhi(hu);
    }

#pragma unroll
    for (int m = 0; m < 2; ++m) {
        const int s0 = rp[m * n + wid];
        const int s1 = rp[m * n + wid + 1];
        const float am  = alpha[m];
        const float arv = arbuf[wid * 2 + m];
        const float bm  = m ? b1 : b0;

        float sum = 0.0f;
        float2 a = {0.0f, 0.0f};

        for (int base = s0; base < s1; base += 64) {
            const int cnt = min(64, s1 - base);

            int   src = 0;
            float ex  = 0.0f;
            if (lane < cnt) {
                src = srcs[base + lane];
                ex  = __expf(am * (albuf[src * 2 + m] + arv));
            }
            {
                float t = ex;
#pragma unroll
                for (int o = 32; o > 0; o >>= 1) t += __shfl_xor(t, o);
                sum += t;
            }

            const unsigned exu = __float_as_uint(ex);
            int j = 0;
            // 8 loads in flight before any consuming FMA (latency hiding)
            for (; j + 8 <= cnt; j += 8) {
                unsigned u[8];
                float    w[8];
#pragma unroll
                for (int q = 0; q < 8; ++q) {
                    int s = __builtin_amdgcn_readlane(src, j + q);
                    w[q]  = __uint_as_float(__builtin_amdgcn_readlane(exu, j + q));
                    u[q]  = h2[(size_t)s * 64 + lane];
                }
#pragma unroll
                for (int q = 0; q < 8; ++q) {
                    a.x = fmaf(w[q], bflo(u[q]), a.x);
                    a.y = fmaf(w[q], bfhi(u[q]), a.y);
                }
            }
            for (; j + 2 <= cnt; j += 2) {
                int   sA = __builtin_amdgcn_readlane(src, j + 0);
                int   sB = __builtin_amdgcn_readlane(src, j + 1);
                float wA = __uint_as_float(__builtin_amdgcn_readlane(exu, j + 0));
                float wB = __uint_as_float(__builtin_amdgcn_readlane(exu, j + 1));
                unsigned uA = h2[(size_t)sA * 64 + lane];
                unsigned uB = h2[(size_t)sB * 64 + lane];
                a.x = fmaf(wA, bflo(uA), a.x); a.y = fmaf(wA, bfhi(uA), a.y);
                a.x = fmaf(wB, bflo(uB), a.x); a.y = fmaf(wB, bfhi(uB), a.y);
            }
            if (j < cnt) {
                int   sA = __builtin_amdgcn_readlane(src, j);
                float wA = __uint_as_float(__builtin_amdgcn_readlane(exu, j));
                unsigned uA = h2[(size_t)sA * 64 + lane];
                a.x = fmaf(wA, bflo(uA), a.x);
                a.y = fmaf(wA, bfhi(uA), a.y);
            }
        }

        float sc = bm / (sum + 1e-16f);
        acc.x = fmaf(sc, a.x, acc.x);
        acc.y = fmaf(sc, a.y, acc.y);
    }

    float2 o;
    o.x = fmaxf(acc.x, 0.0f);
    o.y = fmaxf(acc.y, 0.0f);
    *(float2*)(out + (size_t)wid * DIM + lane * 2) = o;
}

extern "C" void kernel_launch(void* const* d_in, const int* in_sizes, int n_in,
                              void* d_out, int out_size, void* d_ws, size_t ws_size,
                              hipStream_t stream)
{
    const float* x     = (const float*)d_in[0];
    const int*   ei1   = (const int*)d_in[1];
    const int*   ei2   = (const int*)d_in[2];
    const float* W_lin = (const float*)d_in[3];
    const float* b_lin = (const float*)d_in[4];
    const float* W_cv  = (const float*)d_in[5];
    const float* b_cv  = (const float*)d_in[6];
    const float* alw   = (const float*)d_in[7];
    const float* alb   = (const float*)d_in[8];
    const float* arw   = (const float*)d_in[9];
    const float* arb   = (const float*)d_in[10];
    const float* alpha = (const float*)d_in[11];

    const int N    = in_sizes[0] / DIM;
    const int E    = in_sizes[1] / 2;
    const int N2   = 2 * N;
    const int NSEG = (N + HSEG - 1) / HSEG;

    float* out = (float*)d_out;

    // workspace layout (4-byte units)
    unsigned* h2    = (unsigned*)d_ws;                  // N*64
    float*    albuf = (float*)(h2 + (size_t)N * 64);    // 2N
    float*    arbuf = albuf + (size_t)2 * N;            // 2N
    float*    betab = arbuf + (size_t)2 * N;            // 3N
    int*      rp    = (int*)(betab + (size_t)3 * N);    // 2N+2
    int*      cnt   = rp + (N2 + 2);                    // 2N
    int*      bsum  = cnt + N2;                         // 256
    unsigned* pb    = (unsigned*)(bsum + 256);          // 2*NSEG*NSL*WSEG
    int*      srcs  = (int*)(pb + (size_t)2 * NSEG * NSL * WSEG); // 2E

    const int nb     = (N2 + 1023) / 1024;
    const int nhblk  = 2 * NSEG * NSL;

    k_gemm_h<<<(N + 63) / 64, 256, 0, stream>>>(x, W_lin, b_lin,
                                                (unsigned short*)h2, N);

    k_hist<<<nhblk, 256, 0, stream>>>(ei1, ei2, pb, NSEG, N, E);

    k_node_vec<<<(N + 3) / 4, 256, 0, stream>>>(x, h2, W_cv, b_cv, alw, alb,
                                                arw, arb, albuf, arbuf, betab, N);

    k_combine<<<(2 * NSEG * WSEG + 255) / 256, 256, 0, stream>>>(pb, cnt, NSEG, N);

    k_scan1<<<nb, 256, 0, stream>>>(cnt, rp, bsum, N2);
    k_scan2<<<1, 256, 0, stream>>>(bsum, nb);
    k_scan3<<<(N2 + 255) / 256, 256, 0, stream>>>(rp, bsum, N2, 2 * E);

    k_fill<<<nhblk, 256, 0, stream>>>(ei1, ei2, pb, rp, srcs, NSEG, N, E);

    k_gather<<<(N + 3) / 4, 256, 0, stream>>>(h2, albuf, arbuf, betab, alpha,
                                              rp, srcs, out, N);
}

// Round 9
// 288.276 us; speedup vs baseline: 10.3321x; 1.1423x over previous
//
#include <hip/hip_runtime.h>

#define DIM 128
#define NSL 64             // edge slices per metapath
#define HSEG 25000         // nodes per histogram segment
#define WSEG 6250          // HSEG/4 packed-byte words (25 KB LDS)

typedef __attribute__((ext_vector_type(8))) short bf16x8;
typedef __attribute__((ext_vector_type(4))) float f32x4;

__device__ __forceinline__ unsigned bfbits(float f) {
    unsigned u = __float_as_uint(f);
    return (u + 0x7FFFu + ((u >> 16) & 1u)) >> 16;   // RNE bf16
}
__device__ __forceinline__ float bflo(unsigned u) { return __uint_as_float(u << 16); }
__device__ __forceinline__ float bfhi(unsigned u) { return __uint_as_float(u & 0xFFFF0000u); }

// ---- K1: h2(bf16) = x @ W_lin^T + b_lin via MFMA; fused al/beta epilogue ----
__global__ __launch_bounds__(256) void k_gemm_h(
    const float* __restrict__ x, const float* __restrict__ W,
    const float* __restrict__ b, const float* __restrict__ Wc,
    const float* __restrict__ bcv, const float* __restrict__ alw,
    const float* __restrict__ alb, const float* __restrict__ alpha,
    unsigned short* __restrict__ h2u, float* __restrict__ exal0,
    float* __restrict__ exal1, float* __restrict__ betab, int n)
{
    __shared__ short wlds[128 * 136];
    __shared__ short xlds[64 * 136];
    const int tid  = threadIdx.x;
    const int row0 = blockIdx.x * 64;

    {
        const int j = tid >> 1, half = tid & 1;
        const float4* W4 = (const float4*)W;
#pragma unroll
        for (int i = 0; i < 8; ++i) {
            float4 fa = W4[j * 32 + half * 16 + i * 2];
            float4 fb = W4[j * 32 + half * 16 + i * 2 + 1];
            uint4 p;
            p.x = bfbits(fa.x) | (bfbits(fa.y) << 16);
            p.y = bfbits(fa.z) | (bfbits(fa.w) << 16);
            p.z = bfbits(fb.x) | (bfbits(fb.y) << 16);
            p.w = bfbits(fb.z) | (bfbits(fb.w) << 16);
            *(uint4*)&wlds[j * 136 + half * 64 + i * 8] = p;
        }
    }
    {
        const int r = tid >> 2, q = tid & 3;
        const int row = min(row0 + r, n - 1);
        const float4* x4 = (const float4*)x;
#pragma unroll
        for (int i = 0; i < 4; ++i) {
            float4 fa = x4[(size_t)row * 32 + q * 8 + i * 2];
            float4 fb = x4[(size_t)row * 32 + q * 8 + i * 2 + 1];
            uint4 p;
            p.x = bfbits(fa.x) | (bfbits(fa.y) << 16);
            p.y = bfbits(fa.z) | (bfbits(fa.w) << 16);
            p.z = bfbits(fb.x) | (bfbits(fb.y) << 16);
            p.w = bfbits(fb.z) | (bfbits(fb.w) << 16);
            *(uint4*)&xlds[r * 136 + q * 32 + i * 8] = p;
        }
    }
    __syncthreads();

    const int wv = tid >> 6, lane = tid & 63;
    const int lr = lane & 15, lg = lane >> 4;

    f32x4 acc[8];
#pragma unroll
    for (int c = 0; c < 8; ++c) acc[c] = (f32x4){0.f, 0.f, 0.f, 0.f};

#pragma unroll
    for (int ks = 0; ks < 4; ++ks) {
        bf16x8 a = *(const bf16x8*)&xlds[(wv * 16 + lr) * 136 + ks * 32 + lg * 8];
#pragma unroll
        for (int c = 0; c < 8; ++c) {
            bf16x8 bb = *(const bf16x8*)&wlds[(c * 16 + lr) * 136 + ks * 32 + lg * 8];
            acc[c] = __builtin_amdgcn_mfma_f32_16x16x32_bf16(a, bb, acc[c], 0, 0, 0);
        }
    }

    // epilogue: C/D layout col=lane&15, row=(lane>>4)*4+reg  [m89-verified]
    const int rl0 = wv * 16 + lg * 4;      // local row base
    float as0[4] = {0.f,0.f,0.f,0.f}, as1[4] = {0.f,0.f,0.f,0.f};
#pragma unroll
    for (int c = 0; c < 8; ++c) {
        const int col = c * 16 + lr;
        const float bc = b[col];
        const float w0 = alw[col], w1 = alw[128 + col];
#pragma unroll
        for (int r = 0; r < 4; ++r) {
            const float hv = acc[c][r] + bc;
            const int row = row0 + rl0 + r;
            if (row < n)
                h2u[(size_t)row * DIM + col] = (unsigned short)bfbits(hv);
            as0[r] = fmaf(hv, w0, as0[r]);
            as1[r] = fmaf(hv, w1, as1[r]);
        }
    }
    float xs0[4] = {0.f,0.f,0.f,0.f}, xs1[4] = {0.f,0.f,0.f,0.f},
          xs2[4] = {0.f,0.f,0.f,0.f};
#pragma unroll
    for (int i = 0; i < 8; ++i) {
        const int col = lr + i * 16;
        const float wc0 = Wc[col], wc1 = Wc[128 + col], wc2 = Wc[256 + col];
#pragma unroll
        for (int r = 0; r < 4; ++r) {
            const float xv = bflo((unsigned)(unsigned short)xlds[(rl0 + r) * 136 + col]);
            xs0[r] = fmaf(xv, wc0, xs0[r]);
            xs1[r] = fmaf(xv, wc1, xs1[r]);
            xs2[r] = fmaf(xv, wc2, xs2[r]);
        }
    }
#pragma unroll
    for (int o = 1; o <= 8; o <<= 1) {
#pragma unroll
        for (int r = 0; r < 4; ++r) {
            as0[r] += __shfl_xor(as0[r], o);
            as1[r] += __shfl_xor(as1[r], o);
            xs0[r] += __shfl_xor(xs0[r], o);
            xs1[r] += __shfl_xor(xs1[r], o);
            xs2[r] += __shfl_xor(xs2[r], o);
        }
    }
    if (lr == 0) {
        const float a0 = alpha[0], a1 = alpha[1];
        const float ab0 = alb[0], ab1 = alb[1];
        const float b0 = bcv[0], b1 = bcv[1], b2 = bcv[2];
#pragma unroll
        for (int r = 0; r < 4; ++r) {
            const int row = row0 + rl0 + r;
            if (row < n) {
                exal0[row] = __expf(a0 * (as0[r] + ab0));
                exal1[row] = __expf(a1 * (as1[r] + ab1));
                float c0 = xs0[r] + b0, c1 = xs1[r] + b1, c2 = xs2[r] + b2;
                float mx = fmaxf(c0, fmaxf(c1, c2));
                float e0 = __expf(c0 - mx), e1 = __expf(c1 - mx),
                      e2 = __expf(c2 - mx);
                float s = e0 + e1 + e2;
                betab[row * 3 + 0] = e0 / s;
                betab[row * 3 + 1] = e1 / s;
                betab[row * 3 + 2] = e2 / s;
            }
        }
    }
}

// ---------------- K3: per-(metapath,segment,slice) LDS histogram ----------------
__global__ __launch_bounds__(256) void k_hist(
    const int* __restrict__ ei1, const int* __restrict__ ei2,
    unsigned* __restrict__ pb, int nseg, int n, int e)
{
    __shared__ unsigned lds[WSEG];
    const int blk = blockIdx.x;
    const int s   = blk % NSL;
    const int seg = (blk / NSL) % nseg;
    const int m   = blk / (NSL * nseg);
    const int* ei = m ? ei2 : ei1;
    const int d0  = seg * HSEG;
    const int W   = (min(n - d0, HSEG) + 3) >> 2;

    for (int i = threadIdx.x; i < W; i += 256) lds[i] = 0;
    __syncthreads();

    const int sl = (e + NSL - 1) / NSL;
    const int j0 = s * sl, j1 = min(j0 + sl, e);
    for (int j = j0 + threadIdx.x; j < j1; j += 256) {
        int dl = ei[j] - d0;
        if ((unsigned)dl < (unsigned)HSEG)
            atomicAdd(&lds[dl >> 2], 1u << ((dl & 3) * 8));
    }
    __syncthreads();

    unsigned* dst = pb + (size_t)blk * WSEG;
    for (int i = threadIdx.x; i < W; i += 256) dst[i] = lds[i];
}

// ---------------- K4: per-slice exclusive byte-bases + totals ----------------
__global__ __launch_bounds__(256) void k_combine(
    unsigned* __restrict__ pb, int* __restrict__ cnt, int nseg, int n)
{
    int t = blockIdx.x * 256 + threadIdx.x;
    if (t >= 2 * nseg * WSEG) return;
    const int w   = t % WSEG;
    const int seg = (t / WSEG) % nseg;
    const int m   = t / (WSEG * nseg);
    const int d0  = seg * HSEG;

    unsigned run = 0;
    unsigned* base = pb + ((size_t)(m * nseg + seg) * NSL) * WSEG + w;
    for (int s = 0; s < NSL; ++s) {
        unsigned v = base[(size_t)s * WSEG];
        base[(size_t)s * WSEG] = run;   // exclusive byte-base of slice s
        run += v;                       // packed adds; bytes <= ~50, no carry
    }
    int bin = d0 + 4 * w;
    if (bin + 3 < n && 4 * w + 3 < HSEG) {
        int4 c = make_int4(run & 0xFF, (run >> 8) & 0xFF,
                           (run >> 16) & 0xFF, (run >> 24) & 0xFF);
        *(int4*)&cnt[m * n + bin] = c;
    } else {
        for (int j = 0; j < 4 && bin + j < n && 4 * w + j < HSEG; ++j)
            cnt[m * n + bin + j] = (run >> (8 * j)) & 0xFF;
    }
}

// ---------------- K5: exclusive scan over 2N counts (2-level) ----------------
__global__ __launch_bounds__(256) void k_scan1(
    const int* __restrict__ cnt, int* __restrict__ excl,
    int* __restrict__ bsum, int n2)
{
    __shared__ int sh[256];
    int t = threadIdx.x;
    int base = blockIdx.x * 1024 + t * 4;
    int v0 = (base + 0 < n2) ? cnt[base + 0] : 0;
    int v1 = (base + 1 < n2) ? cnt[base + 1] : 0;
    int v2 = (base + 2 < n2) ? cnt[base + 2] : 0;
    int v3 = (base + 3 < n2) ? cnt[base + 3] : 0;
    int s1 = v0 + v1, s2 = s1 + v2, s3 = s2 + v3;
    sh[t] = s3;
    __syncthreads();
    for (int off = 1; off < 256; off <<= 1) {
        int a = (t >= off) ? sh[t - off] : 0;
        __syncthreads();
        sh[t] += a;
        __syncthreads();
    }
    int eb = sh[t] - s3;
    if (t == 255) bsum[blockIdx.x] = sh[255];
    if (base + 0 < n2) excl[base + 0] = eb;
    if (base + 1 < n2) excl[base + 1] = eb + v0;
    if (base + 2 < n2) excl[base + 2] = eb + s1;
    if (base + 3 < n2) excl[base + 3] = eb + s2;
}

__global__ __launch_bounds__(256) void k_scan2(int* __restrict__ bsum, int nb)
{
    __shared__ int sh[256];
    int t = threadIdx.x;
    int v = (t < nb) ? bsum[t] : 0;
    sh[t] = v;
    __syncthreads();
    for (int off = 1; off < 256; off <<= 1) {
        int a = (t >= off) ? sh[t - off] : 0;
        __syncthreads();
        sh[t] += a;
        __syncthreads();
    }
    if (t < nb) bsum[t] = sh[t] - v;
}

__global__ __launch_bounds__(256) void k_scan3(
    int* __restrict__ rp, const int* __restrict__ bsum, int n2, int etot)
{
    int i = blockIdx.x * 256 + threadIdx.x;
    if (i < n2) rp[i] += bsum[i >> 10];
    if (i == 0) rp[n2] = etot;
}

// ---------------- K6: CSR fill via LDS re-rank (no global atomics) ----------------
__global__ __launch_bounds__(256) void k_fill(
    const int* __restrict__ ei1, const int* __restrict__ ei2,
    const unsigned* __restrict__ pb, const int* __restrict__ rp,
    int* __restrict__ srcs, int nseg, int n, int e)
{
    __shared__ unsigned lds[WSEG];
    const int blk = blockIdx.x;
    const int s   = blk % NSL;
    const int seg = (blk / NSL) % nseg;
    const int m   = blk / (NSL * nseg);
    const int* ei = m ? ei2 : ei1;
    const int d0  = seg * HSEG;
    const int W   = (min(n - d0, HSEG) + 3) >> 2;

    for (int i = threadIdx.x; i < W; i += 256) lds[i] = 0;
    __syncthreads();

    const unsigned* sb = pb + (size_t)blk * WSEG;
    const int sl = (e + NSL - 1) / NSL;
    const int j0 = s * sl, j1 = min(j0 + sl, e);
    for (int j = j0 + threadIdx.x; j < j1; j += 256) {
        int d  = ei[j];
        int dl = d - d0;
        if ((unsigned)dl < (unsigned)HSEG) {
            int sv = ei[e + j];
            int sh = (dl & 3) * 8;
            unsigned old = atomicAdd(&lds[dl >> 2], 1u << sh);
            int rank = (old >> sh) & 0xFF;
            int bse  = (sb[dl >> 2] >> sh) & 0xFF;
            srcs[rp[m * n + d] + bse + rank] = sv;
        }
    }
}

// ---------------- K7: fused gather (bf16, 8-deep, exal) + self + relu ------
__global__ __launch_bounds__(256) void k_gather(
    const unsigned* __restrict__ h2,
    const float* __restrict__ exal0, const float* __restrict__ exal1,
    const float* __restrict__ betab,
    const int* __restrict__ rp, const int* __restrict__ srcs,
    float* __restrict__ out, int n)
{
    int wid  = blockIdx.x * 4 + (threadIdx.x >> 6);
    if (wid >= n) return;
    int lane = threadIdx.x & 63;

    float b0 = betab[wid * 3 + 0];
    float b1 = betab[wid * 3 + 1];
    float b2 = betab[wid * 3 + 2];

    float2 acc;
    {
        unsigned hu = h2[(size_t)wid * 64 + lane];
        acc.x = b2 * bflo(hu);
        acc.y = b2 * bfhi(hu);
    }

#pragma unroll
    for (int m = 0; m < 2; ++m) {
        const int s0 = rp[m * n + wid];
        const int s1 = rp[m * n + wid + 1];
        const float* exal = m ? exal1 : exal0;
        const float bm = m ? b1 : b0;

        float sum = 0.0f;
        float2 a = {0.0f, 0.0f};

        for (int base = s0; base < s1; base += 64) {
            const int cnt = min(64, s1 - base);

            int   src = 0;
            float ex  = 0.0f;
            if (lane < cnt) {
                src = srcs[base + lane];
                ex  = exal[src];          // dst-side softmax factor cancels
            }
            {
                float t = ex;
#pragma unroll
                for (int o = 32; o > 0; o >>= 1) t += __shfl_xor(t, o);
                sum += t;
            }

            const unsigned exu = __float_as_uint(ex);
            int j = 0;
            for (; j + 8 <= cnt; j += 8) {
                unsigned u[8];
                float    w[8];
#pragma unroll
                for (int q = 0; q < 8; ++q) {
                    int s = __builtin_amdgcn_readlane(src, j + q);
                    w[q]  = __uint_as_float(__builtin_amdgcn_readlane(exu, j + q));
                    u[q]  = h2[(size_t)s * 64 + lane];
                }
#pragma unroll
                for (int q = 0; q < 8; ++q) {
                    a.x = fmaf(w[q], bflo(u[q]), a.x);
                    a.y = fmaf(w[q], bfhi(u[q]), a.y);
                }
            }
            for (; j + 2 <= cnt; j += 2) {
                int   sA = __builtin_amdgcn_readlane(src, j + 0);
                int   sB = __builtin_amdgcn_readlane(src, j + 1);
                float wA = __uint_as_float(__builtin_amdgcn_readlane(exu, j + 0));
                float wB = __uint_as_float(__builtin_amdgcn_readlane(exu, j + 1));
                unsigned uA = h2[(size_t)sA * 64 + lane];
                unsigned uB = h2[(size_t)sB * 64 + lane];
                a.x = fmaf(wA, bflo(uA), a.x); a.y = fmaf(wA, bfhi(uA), a.y);
                a.x = fmaf(wB, bflo(uB), a.x); a.y = fmaf(wB, bfhi(uB), a.y);
            }
            if (j < cnt) {
                int   sA = __builtin_amdgcn_readlane(src, j);
                float wA = __uint_as_float(__builtin_amdgcn_readlane(exu, j));
                unsigned uA = h2[(size_t)sA * 64 + lane];
                a.x = fmaf(wA, bflo(uA), a.x);
                a.y = fmaf(wA, bfhi(uA), a.y);
            }
        }

        float sc = bm / (sum + 1e-16f);
        acc.x = fmaf(sc, a.x, acc.x);
        acc.y = fmaf(sc, a.y, acc.y);
    }

    float2 o;
    o.x = fmaxf(acc.x, 0.0f);
    o.y = fmaxf(acc.y, 0.0f);
    *(float2*)(out + (size_t)wid * DIM + lane * 2) = o;
}

extern "C" void kernel_launch(void* const* d_in, const int* in_sizes, int n_in,
                              void* d_out, int out_size, void* d_ws, size_t ws_size,
                              hipStream_t stream)
{
    const float* x     = (const float*)d_in[0];
    const int*   ei1   = (const int*)d_in[1];
    const int*   ei2   = (const int*)d_in[2];
    const float* W_lin = (const float*)d_in[3];
    const float* b_lin = (const float*)d_in[4];
    const float* W_cv  = (const float*)d_in[5];
    const float* b_cv  = (const float*)d_in[6];
    const float* alw   = (const float*)d_in[7];
    const float* alb   = (const float*)d_in[8];
    const float* alpha = (const float*)d_in[11];

    const int N    = in_sizes[0] / DIM;
    const int E    = in_sizes[1] / 2;
    const int N2   = 2 * N;
    const int NSEG = (N + HSEG - 1) / HSEG;

    float* out = (float*)d_out;

    // workspace layout (4-byte units)
    unsigned* h2    = (unsigned*)d_ws;                  // N*64
    float*    exal0 = (float*)(h2 + (size_t)N * 64);    // N
    float*    exal1 = exal0 + N;                        // N
    float*    betab = exal1 + N;                        // 3N
    int*      rp    = (int*)(betab + (size_t)3 * N);    // 2N+2
    int*      cnt   = rp + (N2 + 2);                    // 2N
    int*      bsum  = cnt + N2;                         // 256
    unsigned* pb    = (unsigned*)(bsum + 256);          // 2*NSEG*NSL*WSEG
    int*      srcs  = (int*)(pb + (size_t)2 * NSEG * NSL * WSEG); // 2E

    const int nb    = (N2 + 1023) / 1024;
    const int nhblk = 2 * NSEG * NSL;

    k_gemm_h<<<(N + 63) / 64, 256, 0, stream>>>(x, W_lin, b_lin, W_cv, b_cv,
                                                alw, alb, alpha,
                                                (unsigned short*)h2,
                                                exal0, exal1, betab, N);

    k_hist<<<nhblk, 256, 0, stream>>>(ei1, ei2, pb, NSEG, N, E);

    k_combine<<<(2 * NSEG * WSEG + 255) / 256, 256, 0, stream>>>(pb, cnt, NSEG, N);

    k_scan1<<<nb, 256, 0, stream>>>(cnt, rp, bsum, N2);
    k_scan2<<<1, 256, 0, stream>>>(bsum, nb);
    k_scan3<<<(N2 + 255) / 256, 256, 0, stream>>>(rp, bsum, N2, 2 * E);

    k_fill<<<nhblk, 256, 0, stream>>>(ei1, ei2, pb, rp, srcs, NSEG, N, E);

    k_gather<<<(N + 3) / 4, 256, 0, stream>>>(h2, exal0, exal1, betab,
                                              rp, srcs, out, N);
}

// Round 10
// 272.611 us; speedup vs baseline: 10.9258x; 1.0575x over previous
//
#include <hip/hip_runtime.h>

#define DIM 128
#define NSL 128            // edge slices per metapath (256 blocks total, 1/CU)
#define WMAX 25000         // N/4 packed-byte words (100 KB LDS, full N)

typedef __attribute__((ext_vector_type(8))) short bf16x8;
typedef __attribute__((ext_vector_type(4))) float f32x4;

__device__ __forceinline__ unsigned bfbits(float f) {
    unsigned u = __float_as_uint(f);
    return (u + 0x7FFFu + ((u >> 16) & 1u)) >> 16;   // RNE bf16
}
__device__ __forceinline__ float bflo(unsigned u) { return __uint_as_float(u << 16); }
__device__ __forceinline__ float bfhi(unsigned u) { return __uint_as_float(u & 0xFFFF0000u); }

// ---- K1: h2(bf16) = x @ W_lin^T + b_lin via MFMA; fused al/beta epilogue ----
__global__ __launch_bounds__(256) void k_gemm_h(
    const float* __restrict__ x, const float* __restrict__ W,
    const float* __restrict__ b, const float* __restrict__ Wc,
    const float* __restrict__ bcv, const float* __restrict__ alw,
    const float* __restrict__ alb, const float* __restrict__ alpha,
    unsigned short* __restrict__ h2u, float* __restrict__ exal0,
    float* __restrict__ exal1, float* __restrict__ betab, int n)
{
    __shared__ short wlds[128 * 136];
    __shared__ short xlds[64 * 136];
    const int tid  = threadIdx.x;
    const int row0 = blockIdx.x * 64;

    {
        const int j = tid >> 1, half = tid & 1;
        const float4* W4 = (const float4*)W;
#pragma unroll
        for (int i = 0; i < 8; ++i) {
            float4 fa = W4[j * 32 + half * 16 + i * 2];
            float4 fb = W4[j * 32 + half * 16 + i * 2 + 1];
            uint4 p;
            p.x = bfbits(fa.x) | (bfbits(fa.y) << 16);
            p.y = bfbits(fa.z) | (bfbits(fa.w) << 16);
            p.z = bfbits(fb.x) | (bfbits(fb.y) << 16);
            p.w = bfbits(fb.z) | (bfbits(fb.w) << 16);
            *(uint4*)&wlds[j * 136 + half * 64 + i * 8] = p;
        }
    }
    {
        const int r = tid >> 2, q = tid & 3;
        const int row = min(row0 + r, n - 1);
        const float4* x4 = (const float4*)x;
#pragma unroll
        for (int i = 0; i < 4; ++i) {
            float4 fa = x4[(size_t)row * 32 + q * 8 + i * 2];
            float4 fb = x4[(size_t)row * 32 + q * 8 + i * 2 + 1];
            uint4 p;
            p.x = bfbits(fa.x) | (bfbits(fa.y) << 16);
            p.y = bfbits(fa.z) | (bfbits(fa.w) << 16);
            p.z = bfbits(fb.x) | (bfbits(fb.y) << 16);
            p.w = bfbits(fb.z) | (bfbits(fb.w) << 16);
            *(uint4*)&xlds[r * 136 + q * 32 + i * 8] = p;
        }
    }
    __syncthreads();

    const int wv = tid >> 6, lane = tid & 63;
    const int lr = lane & 15, lg = lane >> 4;

    f32x4 acc[8];
#pragma unroll
    for (int c = 0; c < 8; ++c) acc[c] = (f32x4){0.f, 0.f, 0.f, 0.f};

#pragma unroll
    for (int ks = 0; ks < 4; ++ks) {
        bf16x8 a = *(const bf16x8*)&xlds[(wv * 16 + lr) * 136 + ks * 32 + lg * 8];
#pragma unroll
        for (int c = 0; c < 8; ++c) {
            bf16x8 bb = *(const bf16x8*)&wlds[(c * 16 + lr) * 136 + ks * 32 + lg * 8];
            acc[c] = __builtin_amdgcn_mfma_f32_16x16x32_bf16(a, bb, acc[c], 0, 0, 0);
        }
    }

    // epilogue: C/D layout col=lane&15, row=(lane>>4)*4+reg  [m89-verified]
    const int rl0 = wv * 16 + lg * 4;      // local row base
    float as0[4] = {0.f,0.f,0.f,0.f}, as1[4] = {0.f,0.f,0.f,0.f};
#pragma unroll
    for (int c = 0; c < 8; ++c) {
        const int col = c * 16 + lr;
        const float bc = b[col];
        const float w0 = alw[col], w1 = alw[128 + col];
#pragma unroll
        for (int r = 0; r < 4; ++r) {
            const float hv = acc[c][r] + bc;
            const int row = row0 + rl0 + r;
            if (row < n)
                h2u[(size_t)row * DIM + col] = (unsigned short)bfbits(hv);
            as0[r] = fmaf(hv, w0, as0[r]);
            as1[r] = fmaf(hv, w1, as1[r]);
        }
    }
    float xs0[4] = {0.f,0.f,0.f,0.f}, xs1[4] = {0.f,0.f,0.f,0.f},
          xs2[4] = {0.f,0.f,0.f,0.f};
#pragma unroll
    for (int i = 0; i < 8; ++i) {
        const int col = lr + i * 16;
        const float wc0 = Wc[col], wc1 = Wc[128 + col], wc2 = Wc[256 + col];
#pragma unroll
        for (int r = 0; r < 4; ++r) {
            const float xv = bflo((unsigned)(unsigned short)xlds[(rl0 + r) * 136 + col]);
            xs0[r] = fmaf(xv, wc0, xs0[r]);
            xs1[r] = fmaf(xv, wc1, xs1[r]);
            xs2[r] = fmaf(xv, wc2, xs2[r]);
        }
    }
#pragma unroll
    for (int o = 1; o <= 8; o <<= 1) {
#pragma unroll
        for (int r = 0; r < 4; ++r) {
            as0[r] += __shfl_xor(as0[r], o);
            as1[r] += __shfl_xor(as1[r], o);
            xs0[r] += __shfl_xor(xs0[r], o);
            xs1[r] += __shfl_xor(xs1[r], o);
            xs2[r] += __shfl_xor(xs2[r], o);
        }
    }
    if (lr == 0) {
        const float a0 = alpha[0], a1 = alpha[1];
        const float ab0 = alb[0], ab1 = alb[1];
        const float b0 = bcv[0], b1 = bcv[1], b2 = bcv[2];
#pragma unroll
        for (int r = 0; r < 4; ++r) {
            const int row = row0 + rl0 + r;
            if (row < n) {
                exal0[row] = __expf(a0 * (as0[r] + ab0));
                exal1[row] = __expf(a1 * (as1[r] + ab1));
                float c0 = xs0[r] + b0, c1 = xs1[r] + b1, c2 = xs2[r] + b2;
                float mx = fmaxf(c0, fmaxf(c1, c2));
                float e0 = __expf(c0 - mx), e1 = __expf(c1 - mx),
                      e2 = __expf(c2 - mx);
                float s = e0 + e1 + e2;
                betab[row * 3 + 0] = e0 / s;
                betab[row * 3 + 1] = e1 / s;
                betab[row * 3 + 2] = e2 / s;
            }
        }
    }
}

// ---------------- K3: per-(metapath,slice) full-N LDS histogram ----------------
// 1024 threads, 100 KB LDS, 1 block/CU, 16 waves. Each edge read ONCE.
__global__ __launch_bounds__(1024) void k_hist(
    const int* __restrict__ ei1, const int* __restrict__ ei2,
    unsigned* __restrict__ pb, int n, int e)
{
    __shared__ unsigned lds[WMAX];
    const int blk = blockIdx.x;
    const int s   = blk % NSL;
    const int m   = blk / NSL;
    const int* ei = m ? ei2 : ei1;
    const int W   = (n + 3) >> 2;

    for (int i = threadIdx.x; i < W; i += 1024) lds[i] = 0;
    __syncthreads();

    const int sl = (e + NSL - 1) / NSL;
    const int j0 = s * sl, j1 = min(j0 + sl, e);
    for (int j = j0 + threadIdx.x; j < j1; j += 1024) {
        int d = ei[j];
        atomicAdd(&lds[d >> 2], 1u << ((d & 3) * 8));
    }
    __syncthreads();

    unsigned* dst = pb + (size_t)blk * WMAX;
    for (int i = threadIdx.x; i < W; i += 1024) dst[i] = lds[i];
}

// ---------------- K4: per-slice exclusive byte-bases + totals ----------------
__global__ __launch_bounds__(256) void k_combine(
    unsigned* __restrict__ pb, int* __restrict__ cnt, int n)
{
    const int W = (n + 3) >> 2;
    int t = blockIdx.x * 256 + threadIdx.x;
    if (t >= 2 * W) return;
    const int m = t / W, w = t % W;

    unsigned run = 0;
    unsigned* base = pb + ((size_t)m * NSL) * WMAX + w;
    for (int s = 0; s < NSL; ++s) {
        unsigned v = base[(size_t)s * WMAX];
        base[(size_t)s * WMAX] = run;   // exclusive byte-base of slice s
        run += v;                       // packed adds; bytes <= ~50, no carry
    }
    int bin = 4 * w;
    if (bin + 3 < n) {
        int4 c = make_int4(run & 0xFF, (run >> 8) & 0xFF,
                           (run >> 16) & 0xFF, (run >> 24) & 0xFF);
        *(int4*)&cnt[m * n + bin] = c;
    } else {
        for (int j = 0; j < 4 && bin + j < n; ++j)
            cnt[m * n + bin + j] = (run >> (8 * j)) & 0xFF;
    }
}

// ---------------- K5: exclusive scan over 2N counts (2-level) ----------------
__global__ __launch_bounds__(256) void k_scan1(
    const int* __restrict__ cnt, int* __restrict__ excl,
    int* __restrict__ bsum, int n2)
{
    __shared__ int sh[256];
    int t = threadIdx.x;
    int base = blockIdx.x * 1024 + t * 4;
    int v0 = (base + 0 < n2) ? cnt[base + 0] : 0;
    int v1 = (base + 1 < n2) ? cnt[base + 1] : 0;
    int v2 = (base + 2 < n2) ? cnt[base + 2] : 0;
    int v3 = (base + 3 < n2) ? cnt[base + 3] : 0;
    int s1 = v0 + v1, s2 = s1 + v2, s3 = s2 + v3;
    sh[t] = s3;
    __syncthreads();
    for (int off = 1; off < 256; off <<= 1) {
        int a = (t >= off) ? sh[t - off] : 0;
        __syncthreads();
        sh[t] += a;
        __syncthreads();
    }
    int eb = sh[t] - s3;
    if (t == 255) bsum[blockIdx.x] = sh[255];
    if (base + 0 < n2) excl[base + 0] = eb;
    if (base + 1 < n2) excl[base + 1] = eb + v0;
    if (base + 2 < n2) excl[base + 2] = eb + s1;
    if (base + 3 < n2) excl[base + 3] = eb + s2;
}

__global__ __launch_bounds__(256) void k_scan2(int* __restrict__ bsum, int nb)
{
    __shared__ int sh[256];
    int t = threadIdx.x;
    int v = (t < nb) ? bsum[t] : 0;
    sh[t] = v;
    __syncthreads();
    for (int off = 1; off < 256; off <<= 1) {
        int a = (t >= off) ? sh[t - off] : 0;
        __syncthreads();
        sh[t] += a;
        __syncthreads();
    }
    if (t < nb) bsum[t] = sh[t] - v;
}

__global__ __launch_bounds__(256) void k_scan3(
    int* __restrict__ rp, const int* __restrict__ bsum, int n2, int etot)
{
    int i = blockIdx.x * 256 + threadIdx.x;
    if (i < n2) rp[i] += bsum[i >> 10];
    if (i == 0) rp[n2] = etot;
}

// ---------------- K6: CSR fill via LDS re-rank (no global atomics) ----------------
__global__ __launch_bounds__(1024) void k_fill(
    const int* __restrict__ ei1, const int* __restrict__ ei2,
    const unsigned* __restrict__ pb, const int* __restrict__ rp,
    int* __restrict__ srcs, int n, int e)
{
    __shared__ unsigned lds[WMAX];
    const int blk = blockIdx.x;
    const int s   = blk % NSL;
    const int m   = blk / NSL;
    const int* ei = m ? ei2 : ei1;
    const int W   = (n + 3) >> 2;

    for (int i = threadIdx.x; i < W; i += 1024) lds[i] = 0;
    __syncthreads();

    const unsigned* sb = pb + (size_t)blk * WMAX;
    const int sl = (e + NSL - 1) / NSL;
    const int j0 = s * sl, j1 = min(j0 + sl, e);
    for (int j = j0 + threadIdx.x; j < j1; j += 1024) {
        int d  = ei[j];
        int sv = ei[e + j];
        int sh = (d & 3) * 8;
        unsigned old = atomicAdd(&lds[d >> 2], 1u << sh);
        int rank = (old >> sh) & 0xFF;
        int bse  = (sb[d >> 2] >> sh) & 0xFF;
        srcs[rp[m * n + d] + bse + rank] = sv;
    }
}

// ---------------- K7: fused gather (bf16, 8-deep, exal) + self + relu ------
__global__ __launch_bounds__(256) void k_gather(
    const unsigned* __restrict__ h2,
    const float* __restrict__ exal0, const float* __restrict__ exal1,
    const float* __restrict__ betab,
    const int* __restrict__ rp, const int* __restrict__ srcs,
    float* __restrict__ out, int n)
{
    int wid  = blockIdx.x * 4 + (threadIdx.x >> 6);
    if (wid >= n) return;
    int lane = threadIdx.x & 63;

    float b0 = betab[wid * 3 + 0];
    float b1 = betab[wid * 3 + 1];
    float b2 = betab[wid * 3 + 2];

    float2 acc;
    {
        unsigned hu = h2[(size_t)wid * 64 + lane];
        acc.x = b2 * bflo(hu);
        acc.y = b2 * bfhi(hu);
    }

#pragma unroll
    for (int m = 0; m < 2; ++m) {
        const int s0 = rp[m * n + wid];
        const int s1 = rp[m * n + wid + 1];
        const float* exal = m ? exal1 : exal0;
        const float bm = m ? b1 : b0;

        float sum = 0.0f;
        float2 a = {0.0f, 0.0f};

        for (int base = s0; base < s1; base += 64) {
            const int cnt = min(64, s1 - base);

            int   src = 0;
            float ex  = 0.0f;
            if (lane < cnt) {
                src = srcs[base + lane];
                ex  = exal[src];          // dst-side softmax factor cancels
            }
            {
                float t = ex;
#pragma unroll
                for (int o = 32; o > 0; o >>= 1) t += __shfl_xor(t, o);
                sum += t;
            }

            const unsigned exu = __float_as_uint(ex);
            int j = 0;
            for (; j + 8 <= cnt; j += 8) {
                unsigned u[8];
                float    w[8];
#pragma unroll
                for (int q = 0; q < 8; ++q) {
                    int s = __builtin_amdgcn_readlane(src, j + q);
                    w[q]  = __uint_as_float(__builtin_amdgcn_readlane(exu, j + q));
                    u[q]  = h2[(size_t)s * 64 + lane];
                }
#pragma unroll
                for (int q = 0; q < 8; ++q) {
                    a.x = fmaf(w[q], bflo(u[q]), a.x);
                    a.y = fmaf(w[q], bfhi(u[q]), a.y);
                }
            }
            for (; j + 2 <= cnt; j += 2) {
                int   sA = __builtin_amdgcn_readlane(src, j + 0);
                int   sB = __builtin_amdgcn_readlane(src, j + 1);
                float wA = __uint_as_float(__builtin_amdgcn_readlane(exu, j + 0));
                float wB = __uint_as_float(__builtin_amdgcn_readlane(exu, j + 1));
                unsigned uA = h2[(size_t)sA * 64 + lane];
                unsigned uB = h2[(size_t)sB * 64 + lane];
                a.x = fmaf(wA, bflo(uA), a.x); a.y = fmaf(wA, bfhi(uA), a.y);
                a.x = fmaf(wB, bflo(uB), a.x); a.y = fmaf(wB, bfhi(uB), a.y);
            }
            if (j < cnt) {
                int   sA = __builtin_amdgcn_readlane(src, j);
                float wA = __uint_as_float(__builtin_amdgcn_readlane(exu, j));
                unsigned uA = h2[(size_t)sA * 64 + lane];
                a.x = fmaf(wA, bflo(uA), a.x);
                a.y = fmaf(wA, bfhi(uA), a.y);
            }
        }

        float sc = bm / (sum + 1e-16f);
        acc.x = fmaf(sc, a.x, acc.x);
        acc.y = fmaf(sc, a.y, acc.y);
    }

    float2 o;
    o.x = fmaxf(acc.x, 0.0f);
    o.y = fmaxf(acc.y, 0.0f);
    *(float2*)(out + (size_t)wid * DIM + lane * 2) = o;
}

extern "C" void kernel_launch(void* const* d_in, const int* in_sizes, int n_in,
                              void* d_out, int out_size, void* d_ws, size_t ws_size,
                              hipStream_t stream)
{
    const float* x     = (const float*)d_in[0];
    const int*   ei1   = (const int*)d_in[1];
    const int*   ei2   = (const int*)d_in[2];
    const float* W_lin = (const float*)d_in[3];
    const float* b_lin = (const float*)d_in[4];
    const float* W_cv  = (const float*)d_in[5];
    const float* b_cv  = (const float*)d_in[6];
    const float* alw   = (const float*)d_in[7];
    const float* alb   = (const float*)d_in[8];
    const float* alpha = (const float*)d_in[11];

    const int N  = in_sizes[0] / DIM;
    const int E  = in_sizes[1] / 2;
    const int N2 = 2 * N;
    const int W  = (N + 3) >> 2;

    float* out = (float*)d_out;

    // workspace layout (4-byte units)
    unsigned* h2    = (unsigned*)d_ws;                  // N*64
    float*    exal0 = (float*)(h2 + (size_t)N * 64);    // N
    float*    exal1 = exal0 + N;                        // N
    float*    betab = exal1 + N;                        // 3N
    int*      rp    = (int*)(betab + (size_t)3 * N);    // 2N+2
    int*      cnt   = rp + (N2 + 2);                    // 2N
    int*      bsum  = cnt + N2;                         // 256
    unsigned* pb    = (unsigned*)(bsum + 256);          // 2*NSL*WMAX
    int*      srcs  = (int*)(pb + (size_t)2 * NSL * WMAX); // 2E

    const int nb = (N2 + 1023) / 1024;

    k_gemm_h<<<(N + 63) / 64, 256, 0, stream>>>(x, W_lin, b_lin, W_cv, b_cv,
                                                alw, alb, alpha,
                                                (unsigned short*)h2,
                                                exal0, exal1, betab, N);

    k_hist<<<2 * NSL, 1024, 0, stream>>>(ei1, ei2, pb, N, E);

    k_combine<<<(2 * W + 255) / 256, 256, 0, stream>>>(pb, cnt, N);

    k_scan1<<<nb, 256, 0, stream>>>(cnt, rp, bsum, N2);
    k_scan2<<<1, 256, 0, stream>>>(bsum, nb);
    k_scan3<<<(N2 + 255) / 256, 256, 0, stream>>>(rp, bsum, N2, 2 * E);

    k_fill<<<2 * NSL, 1024, 0, stream>>>(ei1, ei2, pb, rp, srcs, N, E);

    k_gather<<<(N + 3) / 4, 256, 0, stream>>>(h2, exal0, exal1, betab,
                                              rp, srcs, out, N);
}